// Round 3
// baseline (265.985 us; speedup 1.0000x reference)
//
#include <hip/hip_runtime.h>
#include <math.h>

#define BB 64
#define D0 768
#define D2 2304
#define HH 512
#define BBHH (BB*HH)
#define NG0 8192
#define NC0 8
#define NCH1 11
#define TK1 32
#define TK2 64
#define NC1 (TK1*NC0)   /* 256 */
#define NC2 (TK2*NCH1)  /* 704 */
#define SP0 6
#define SP1 6
#define SP2 18
#define NBLK 256

__device__ __forceinline__ float sigmoidf_(float x){ return 1.0f/(1.0f+expf(-x)); }
__device__ __forceinline__ float geluf_(float x){ return 0.5f*x*(1.0f+erff(x*0.70710678118654752f)); }
__device__ __forceinline__ unsigned long long maxu64_(unsigned long long a, unsigned long long b){ return a>b?a:b; }

// grid barrier: slot = 128B-strided {cnt @+0, flag @+64B}, pre-zeroed by memset.
// Safe: 256 blocks x 256 thr always co-resident on 256 CUs (capacity >= 8/CU).
__device__ __forceinline__ void gridbar(unsigned* bar, int slot){
  __syncthreads();
  if (threadIdx.x==0){
    unsigned* cnt  = bar + (size_t)slot*32;
    unsigned* flag = cnt + 16;
    __threadfence();
    unsigned old = __hip_atomic_fetch_add(cnt, 1u, __ATOMIC_ACQ_REL, __HIP_MEMORY_SCOPE_AGENT);
    if (old == NBLK-1u){
      __hip_atomic_store(flag, 1u, __ATOMIC_RELEASE, __HIP_MEMORY_SCOPE_AGENT);
    } else {
      while (__hip_atomic_load(flag, __ATOMIC_ACQUIRE, __HIP_MEMORY_SCOPE_AGENT) == 0u)
        __builtin_amdgcn_s_sleep(8);
    }
    __threadfence();
  }
  __syncthreads();
}

// Block-wide bitonic sort of 256 u64 keys, DESCENDING. One key per thread.
__device__ __forceinline__ unsigned long long bitonic256_desc(
    unsigned long long key, int tid, unsigned long long* sbuf)
{
  #pragma unroll
  for (int k = 2; k <= 256; k <<= 1) {
    #pragma unroll
    for (int j = k >> 1; j > 0; j >>= 1) {
      unsigned long long other;
      if (j >= 64) {
        __syncthreads();
        sbuf[tid] = key;
        __syncthreads();
        other = sbuf[tid ^ j];
      } else {
        other = __shfl_xor(key, j, 64);
      }
      bool keep_max = ((tid & j) == 0) == ((tid & k) == 0);
      key = keep_max ? (key > other ? key : other)
                     : (key < other ? key : other);
    }
  }
  return key;
}

__global__ __launch_bounds__(256) void mega_kernel(
    const float* __restrict__ feat5, const float* __restrict__ feat8,
    const float* __restrict__ featcat,
    const float* __restrict__ W0, const float* __restrict__ b0v,
    const float* __restrict__ W1, const float* __restrict__ b1v,
    const float* __restrict__ W2, const float* __restrict__ b2v,
    const float* __restrict__ E0, const float* __restrict__ E1,
    const float* __restrict__ E2,
    const int* __restrict__ g0, const int* __restrict__ g1,
    unsigned* __restrict__ bar,
    float* __restrict__ P, float* __restrict__ h1buf, float* __restrict__ h2buf,
    int* __restrict__ cands1_i, float* __restrict__ gsc1,
    int* __restrict__ cands2_i, float* __restrict__ gsc2,
    float* __restrict__ o_p0, float* __restrict__ o_p1, float* __restrict__ o_p2,
    float* __restrict__ o_w1, float* __restrict__ o_w2,
    float* __restrict__ o_c1, float* __restrict__ o_c2)
{
  __shared__ __align__(16) char smem[17408];
  const int bid = blockIdx.x;
  const int tid = threadIdx.x;
  const int lane = tid & 63, wid = tid >> 6;

  // ================= Phase A: split-k partial GEMMs (240 tasks) ============
  if (bid < 240) {
    const float* X; const float* W; int Dm, split, tile; float* Pb;
    if (bid < 48)      { X=feat5;   W=W0; Dm=D0; split=bid%6;  tile=bid/6;
                         Pb=P + (size_t)split*BBHH; }
    else if (bid < 96) { int l=bid-48; X=feat8; W=W1; Dm=D0; split=l%6; tile=l/6;
                         Pb=P + (size_t)(SP0+split)*BBHH; }
    else               { int l=bid-96; X=featcat; W=W2; Dm=D2; split=l%18; tile=l/18;
                         Pb=P + (size_t)(SP0+SP1+split)*BBHH; }
    int k0 = split*128;
    int jt = tile*64;
    float (*At)[68] = (float(*)[68])smem;
    float (*Bt)[68] = (float(*)[68])(smem + 8704);
    int ti = tid >> 4, tj = tid & 15;
    float acc[4][4] = {};
    for (int ks = 0; ks < 128; ks += 32) {
      #pragma unroll
      for (int it = 0; it < 2; ++it) {
        int q = tid + it*256;
        int b = q & 63, kq = q >> 6;
        float4 v = *(const float4*)(X + (size_t)b*Dm + k0 + ks + kq*4);
        At[kq*4+0][b]=v.x; At[kq*4+1][b]=v.y; At[kq*4+2][b]=v.z; At[kq*4+3][b]=v.w;
      }
      #pragma unroll
      for (int it = 0; it < 2; ++it) {
        int q = tid + it*256;
        int j4 = q & 15, kk = q >> 4;
        float4 v = *(const float4*)(W + (size_t)(k0+ks+kk)*HH + jt + j4*4);
        *(float4*)&Bt[kk][j4*4] = v;
      }
      __syncthreads();
      #pragma unroll
      for (int k = 0; k < 32; ++k) {
        float4 a = *(const float4*)&At[k][ti*4];
        float4 b = *(const float4*)&Bt[k][tj*4];
        float av[4] = {a.x,a.y,a.z,a.w};
        float bv[4] = {b.x,b.y,b.z,b.w};
        #pragma unroll
        for (int r=0;r<4;++r)
          #pragma unroll
          for (int c=0;c<4;++c) acc[r][c] += av[r]*bv[c];
      }
      __syncthreads();
    }
    #pragma unroll
    for (int r=0;r<4;++r)
      #pragma unroll
      for (int c=0;c<4;++c)
        Pb[(size_t)(ti*4+r)*HH + jt + tj*4 + c] = acc[r][c];
  }

  gridbar(bar, 0);

  // ================= Phase B: level0 (256 tasks) ===========================
  {
    int btile = bid & 1;
    int gt = bid >> 1;
    float (*At)[36] = (float(*)[36])smem;
    float (*Bt)[68] = (float(*)[68])(smem + 4608);
    int ti = tid >> 4, tj = tid & 15;
    float acc[2][4] = {};
    for (int ks = 0; ks < HH; ks += 32) {
      {
        int bb = tid & 31, kq = tid >> 5;
        float4 a = make_float4(0.f,0.f,0.f,0.f);
        #pragma unroll
        for (int s=0;s<SP0;++s){
          const float4 p = *(const float4*)(P + (size_t)s*BBHH
                             + (size_t)(btile*32+bb)*HH + ks + kq*4);
          a.x+=p.x; a.y+=p.y; a.z+=p.z; a.w+=p.w;
        }
        float4 bv = *(const float4*)(b0v + ks + kq*4);
        At[kq*4+0][bb]=geluf_(a.x+bv.x);
        At[kq*4+1][bb]=geluf_(a.y+bv.y);
        At[kq*4+2][bb]=geluf_(a.z+bv.z);
        At[kq*4+3][bb]=geluf_(a.w+bv.w);
      }
      #pragma unroll
      for (int it=0; it<2; ++it) {
        int q = tid + it*256; int g = q & 63, kq = q >> 6;
        float4 v = *(const float4*)(E0 + (size_t)(gt*64+g)*HH + ks + kq*4);
        Bt[kq*4+0][g]=v.x; Bt[kq*4+1][g]=v.y; Bt[kq*4+2][g]=v.z; Bt[kq*4+3][g]=v.w;
      }
      __syncthreads();
      #pragma unroll
      for (int k=0;k<32;++k) {
        float2 a = *(const float2*)&At[k][ti*2];
        float4 b = *(const float4*)&Bt[k][tj*4];
        float av[2] = {a.x,a.y};
        float bv[4] = {b.x,b.y,b.z,b.w};
        #pragma unroll
        for (int r=0;r<2;++r)
          #pragma unroll
          for (int c=0;c<4;++c) acc[r][c] += av[r]*bv[c];
      }
      __syncthreads();
    }
    #pragma unroll
    for (int r=0;r<2;++r)
      #pragma unroll
      for (int c=0;c<4;++c)
        o_p0[(size_t)(btile*32 + ti*2 + r)*NG0 + gt*64 + tj*4 + c] = sigmoidf_(acc[r][c]);
  }

  gridbar(bar, 1);

  // ================= Phase C: topk1 + h1 (blocks 0..63) ====================
  if (bid < 64) {
    int b = bid;
    {
      int j = tid*2;
      float ax=0.f, ay=0.f;
      #pragma unroll
      for (int s=0;s<SP1;++s){
        float2 v = *(const float2*)(P + (size_t)(SP0+s)*BBHH + (size_t)b*HH + j);
        ax += v.x; ay += v.y;
      }
      float2 bv = *(const float2*)(b1v + j);
      h1buf[(size_t)b*HH + j]   = geluf_(ax + bv.x);
      h1buf[(size_t)b*HH + j+1] = geluf_(ay + bv.y);
    }
    const float* row = o_p0 + (size_t)b*NG0;
    const float4* rp = (const float4*)(row + tid*32);
    unsigned long long m = 0ull;
    #pragma unroll
    for (int t=0;t<8;++t){
      float4 v = rp[t];
      unsigned i0 = (unsigned)(tid*32 + t*4);
      m = maxu64_(m, ((unsigned long long)__float_as_uint(v.x)<<32) | (unsigned long long)(0xFFFFFFFFu-(i0+0)));
      m = maxu64_(m, ((unsigned long long)__float_as_uint(v.y)<<32) | (unsigned long long)(0xFFFFFFFFu-(i0+1)));
      m = maxu64_(m, ((unsigned long long)__float_as_uint(v.z)<<32) | (unsigned long long)(0xFFFFFFFFu-(i0+2)));
      m = maxu64_(m, ((unsigned long long)__float_as_uint(v.w)<<32) | (unsigned long long)(0xFFFFFFFFu-(i0+3)));
    }
    unsigned long long* sbuf  = (unsigned long long*)smem;
    unsigned long long* slist = (unsigned long long*)(smem + 2048);
    float* s_sc = (float*)(smem + 4096);
    int*   s_idx = (int*)(smem + 4224);
    int*   scnt = (int*)(smem + 4352);
    if (tid==0) *scnt = 0;
    __syncthreads();
    unsigned long long sk = bitonic256_desc(m, tid, sbuf);
    __syncthreads();
    sbuf[tid] = sk;
    __syncthreads();
    unsigned long long t32 = sbuf[31];
    __syncthreads();
    #pragma unroll
    for (int t=0;t<8;++t){
      float4 v = rp[t];
      unsigned i0 = (unsigned)(tid*32 + t*4);
      unsigned long long k0 = ((unsigned long long)__float_as_uint(v.x)<<32) | (unsigned long long)(0xFFFFFFFFu-(i0+0));
      unsigned long long k1 = ((unsigned long long)__float_as_uint(v.y)<<32) | (unsigned long long)(0xFFFFFFFFu-(i0+1));
      unsigned long long k2 = ((unsigned long long)__float_as_uint(v.z)<<32) | (unsigned long long)(0xFFFFFFFFu-(i0+2));
      unsigned long long k3 = ((unsigned long long)__float_as_uint(v.w)<<32) | (unsigned long long)(0xFFFFFFFFu-(i0+3));
      if (k0 >= t32) { int p = atomicAdd(scnt,1); if (p<256) slist[p]=k0; }
      if (k1 >= t32) { int p = atomicAdd(scnt,1); if (p<256) slist[p]=k1; }
      if (k2 >= t32) { int p = atomicAdd(scnt,1); if (p<256) slist[p]=k2; }
      if (k3 >= t32) { int p = atomicAdd(scnt,1); if (p<256) slist[p]=k3; }
    }
    __syncthreads();
    int cnt = *scnt;
    unsigned long long key2 = (tid < cnt) ? slist[tid] : 0ull;
    key2 = bitonic256_desc(key2, tid, sbuf);
    __syncthreads();
    sbuf[tid] = key2;
    __syncthreads();
    if (tid < TK1) {
      unsigned long long w = sbuf[tid];
      s_idx[tid] = (int)(0xFFFFFFFFu - (unsigned)(w & 0xFFFFFFFFull));
      s_sc[tid]  = __uint_as_float((unsigned)(w>>32));
    }
    __syncthreads();
    if (tid < NC1) {
      int k = tid >> 3, c = tid & 7;
      int cand = g0[(size_t)s_idx[k]*NC0 + c];
      cands1_i[(size_t)b*NC1+tid] = cand;
      gsc1[(size_t)b*NC1+tid] = s_sc[k];
      out_of_line: ;
      o_c1[(size_t)b*NC1+tid] = (float)cand;
    }
  }

  gridbar(bar, 2);

  // ================= Phase D: level1 gather-GEMV (256 x 4 tasks) ===========
  {
    int b = bid & 63;
    const float4* h4 = (const float4*)(h1buf + (size_t)b*HH);
    float4 ha = h4[lane*2], hb = h4[lane*2+1];
    #pragma unroll
    for (int j=0;j<4;++j){
      int ytile = (bid >> 6) + 4*j;     // 0..15
      int cbase = ytile*16 + wid*4;
      const int* ci = cands1_i + (size_t)b*NC1 + cbase;
      int id0=ci[0], id1=ci[1], id2=ci[2], id3=ci[3];
      const float4* e0 = (const float4*)(E1 + (size_t)id0*HH);
      const float4* e1 = (const float4*)(E1 + (size_t)id1*HH);
      const float4* e2 = (const float4*)(E1 + (size_t)id2*HH);
      const float4* e3 = (const float4*)(E1 + (size_t)id3*HH);
      float4 a0=e0[lane*2], c0=e0[lane*2+1];
      float4 a1=e1[lane*2], c1=e1[lane*2+1];
      float4 a2=e2[lane*2], c2=e2[lane*2+1];
      float4 a3=e3[lane*2], c3=e3[lane*2+1];
      float s0 = ha.x*a0.x+ha.y*a0.y+ha.z*a0.z+ha.w*a0.w + hb.x*c0.x+hb.y*c0.y+hb.z*c0.z+hb.w*c0.w;
      float s1 = ha.x*a1.x+ha.y*a1.y+ha.z*a1.z+ha.w*a1.w + hb.x*c1.x+hb.y*c1.y+hb.z*c1.z+hb.w*c1.w;
      float s2 = ha.x*a2.x+ha.y*a2.y+ha.z*a2.z+ha.w*a2.w + hb.x*c2.x+hb.y*c2.y+hb.z*c2.z+hb.w*c2.w;
      float s3 = ha.x*a3.x+ha.y*a3.y+ha.z*a3.z+ha.w*a3.w + hb.x*c3.x+hb.y*c3.y+hb.z*c3.z+hb.w*c3.w;
      #pragma unroll
      for (int off=1; off<64; off<<=1) {
        s0 += __shfl_xor(s0, off);
        s1 += __shfl_xor(s1, off);
        s2 += __shfl_xor(s2, off);
        s3 += __shfl_xor(s3, off);
      }
      if (lane==0) {
        const float* gs = gsc1 + (size_t)b*NC1 + cbase;
        float p;
        p = sigmoidf_(s0); o_p1[(size_t)b*NC1+cbase+0]=p; o_w1[(size_t)b*NC1+cbase+0]=p*gs[0];
        p = sigmoidf_(s1); o_p1[(size_t)b*NC1+cbase+1]=p; o_w1[(size_t)b*NC1+cbase+1]=p*gs[1];
        p = sigmoidf_(s2); o_p1[(size_t)b*NC1+cbase+2]=p; o_w1[(size_t)b*NC1+cbase+2]=p*gs[2];
        p = sigmoidf_(s3); o_p1[(size_t)b*NC1+cbase+3]=p; o_w1[(size_t)b*NC1+cbase+3]=p*gs[3];
      }
    }
  }

  gridbar(bar, 3);

  // ================= Phase E: topk2 + h2 (blocks 0..63) ====================
  if (bid < 64) {
    int b = bid;
    {
      int j = tid*2;
      float ax=0.f, ay=0.f;
      #pragma unroll
      for (int s=0;s<SP2;++s){
        float2 v = *(const float2*)(P + (size_t)(SP0+SP1+s)*BBHH + (size_t)b*HH + j);
        ax += v.x; ay += v.y;
      }
      float2 bv = *(const float2*)(b2v + j);
      h2buf[(size_t)b*HH + j]   = geluf_(ax + bv.x);
      h2buf[(size_t)b*HH + j+1] = geluf_(ay + bv.y);
    }
    float v = o_p1[(size_t)b*NC1 + tid];
    unsigned long long key = ((unsigned long long)__float_as_uint(v)<<32) |
                             (unsigned long long)(0xFFFFFFFFu - (unsigned)tid);
    unsigned long long* sbuf = (unsigned long long*)smem;
    float* s_sc = (float*)(smem + 2048);
    int*   s_idx = (int*)(smem + 2304);
    key = bitonic256_desc(key, tid, sbuf);
    __syncthreads();
    sbuf[tid] = key;
    __syncthreads();
    if (tid < TK2) {
      unsigned long long w = sbuf[tid];
      s_idx[tid] = (int)(0xFFFFFFFFu - (unsigned)(w & 0xFFFFFFFFull));
      s_sc[tid]  = __uint_as_float((unsigned)(w>>32));
    }
    __syncthreads();
    for (int e=tid; e<NC2; e+=256) {
      int k = e/NCH1, c = e - k*NCH1;
      int meta = cands1_i[(size_t)b*NC1 + s_idx[k]];
      int cand = g1[(size_t)meta*NCH1 + c];
      cands2_i[(size_t)b*NC2+e] = cand;
      gsc2[(size_t)b*NC2+e] = s_sc[k];
      o_c2[(size_t)b*NC2+e] = (float)cand;
    }
  }

  gridbar(bar, 4);

  // ================= Phase F: level2 gather-GEMV (256 x 11 tasks) ==========
  {
    int b = bid & 63;
    const float4* h4 = (const float4*)(h2buf + (size_t)b*HH);
    float4 ha = h4[lane*2], hb = h4[lane*2+1];
    #pragma unroll
    for (int j=0;j<11;++j){
      int ytile = (bid >> 6) + 4*j;     // 0..43
      int cbase = ytile*16 + wid*4;
      const int* ci = cands2_i + (size_t)b*NC2 + cbase;
      int id0=ci[0], id1=ci[1], id2=ci[2], id3=ci[3];
      const float4* e0 = (const float4*)(E2 + (size_t)id0*HH);
      const float4* e1 = (const float4*)(E2 + (size_t)id1*HH);
      const float4* e2 = (const float4*)(E2 + (size_t)id2*HH);
      const float4* e3 = (const float4*)(E2 + (size_t)id3*HH);
      float4 a0=e0[lane*2], c0=e0[lane*2+1];
      float4 a1=e1[lane*2], c1=e1[lane*2+1];
      float4 a2=e2[lane*2], c2=e2[lane*2+1];
      float4 a3=e3[lane*2], c3=e3[lane*2+1];
      float s0 = ha.x*a0.x+ha.y*a0.y+ha.z*a0.z+ha.w*a0.w + hb.x*c0.x+hb.y*c0.y+hb.z*c0.z+hb.w*c0.w;
      float s1 = ha.x*a1.x+ha.y*a1.y+ha.z*a1.z+ha.w*a1.w + hb.x*c1.x+hb.y*c1.y+hb.z*c1.z+hb.w*c1.w;
      float s2 = ha.x*a2.x+ha.y*a2.y+ha.z*a2.z+ha.w*a2.w + hb.x*c2.x+hb.y*c2.y+hb.z*c2.z+hb.w*c2.w;
      float s3 = ha.x*a3.x+ha.y*a3.y+ha.z*a3.z+ha.w*a3.w + hb.x*c3.x+hb.y*c3.y+hb.z*c3.z+hb.w*c3.w;
      #pragma unroll
      for (int off=1; off<64; off<<=1) {
        s0 += __shfl_xor(s0, off);
        s1 += __shfl_xor(s1, off);
        s2 += __shfl_xor(s2, off);
        s3 += __shfl_xor(s3, off);
      }
      if (lane==0) {
        const float* gs = gsc2 + (size_t)b*NC2 + cbase;
        float p;
        p = (s0==0.0f)?0.0f:sigmoidf_(s0); o_p2[(size_t)b*NC2+cbase+0]=p; o_w2[(size_t)b*NC2+cbase+0]=p*gs[0];
        p = (s1==0.0f)?0.0f:sigmoidf_(s1); o_p2[(size_t)b*NC2+cbase+1]=p; o_w2[(size_t)b*NC2+cbase+1]=p*gs[1];
        p = (s2==0.0f)?0.0f:sigmoidf_(s2); o_p2[(size_t)b*NC2+cbase+2]=p; o_w2[(size_t)b*NC2+cbase+2]=p*gs[2];
        p = (s3==0.0f)?0.0f:sigmoidf_(s3); o_p2[(size_t)b*NC2+cbase+3]=p; o_w2[(size_t)b*NC2+cbase+3]=p*gs[3];
      }
    }
  }
}

extern "C" void kernel_launch(void* const* d_in, const int* in_sizes, int n_in,
                              void* d_out, int out_size, void* d_ws, size_t ws_size,
                              hipStream_t stream) {
  const float* feat5   = (const float*)d_in[0];
  const float* feat8   = (const float*)d_in[1];
  const float* featcat = (const float*)d_in[2];
  const float* W0 = (const float*)d_in[3];
  const float* b0 = (const float*)d_in[4];
  const float* W1 = (const float*)d_in[5];
  const float* b1 = (const float*)d_in[6];
  const float* W2 = (const float*)d_in[7];
  const float* b2 = (const float*)d_in[8];
  const float* E0 = (const float*)d_in[9];
  const float* E1 = (const float*)d_in[10];
  const float* E2 = (const float*)d_in[11];
  const int*   g0 = (const int*)d_in[12];
  const int*   g1 = (const int*)d_in[13];

  float* out = (float*)d_out;
  float* ws  = (float*)d_ws;

  // ws layout (floats)
  size_t off = 0;
  unsigned* bar = (unsigned*)(ws);        off += 256;   // 5 slots in 1 KiB
  float* P    = ws + off; off += (size_t)(SP0+SP1+SP2)*BBHH;
  float* h1   = ws + off; off += BBHH;
  float* h2   = ws + off; off += BBHH;
  int*   cands1_i = (int*)(ws + off); off += (size_t)BB*NC1;
  float* gsc1 = ws + off; off += (size_t)BB*NC1;
  int*   cands2_i = (int*)(ws + off); off += (size_t)BB*NC2;
  float* gsc2 = ws + off; off += (size_t)BB*NC2;

  float* o_p0 = out;
  float* o_p1 = o_p0 + (size_t)BB*NG0;
  float* o_p2 = o_p1 + (size_t)BB*NC1;
  float* o_w1 = o_p2 + (size_t)BB*NC2;
  float* o_w2 = o_w1 + (size_t)BB*NC1;
  float* o_c1 = o_w2 + (size_t)BB*NC2;
  float* o_c2 = o_c1 + (size_t)BB*NC1;

  hipMemsetAsync(bar, 0, 1024, stream);
  mega_kernel<<<dim3(NBLK), dim3(256), 0, stream>>>(
      feat5, feat8, featcat, W0, b0, W1, b1, W2, b2, E0, E1, E2, g0, g1,
      bar, P, h1, h2, cands1_i, gsc1, cands2_i, gsc2,
      o_p0, o_p1, o_p2, o_w1, o_w2, o_c1, o_c2);
}

// Round 4
// 141.902 us; speedup vs baseline: 1.8744x; 1.8744x over previous
//
#include <hip/hip_runtime.h>
#include <math.h>

#define BB 64
#define D0 768
#define D2 2304
#define HH 512
#define BBHH (BB*HH)
#define NG0 8192
#define NC0 8
#define NCH1 11
#define TK1 32
#define TK2 64
#define NC1 (TK1*NC0)   /* 256 */
#define NC2 (TK2*NCH1)  /* 704 */
#define SPA 2    /* k-splits for h0 (768 = 2*384) */
#define SPB 2    /* k-splits for h1 */
#define SPC 18   /* k-splits for h2 (2304 = 18*128) */
#define NSL (SPA+SPB+SPC)   /* 22 P slices */
#define NBLK 256

__device__ __forceinline__ float sigmoidf_(float x){ return 1.0f/(1.0f+expf(-x)); }
__device__ __forceinline__ float geluf_(float x){ return 0.5f*x*(1.0f+erff(x*0.70710678118654752f)); }
__device__ __forceinline__ unsigned long long maxu64_(unsigned long long a, unsigned long long b){ return a>b?a:b; }

// Grid barrier. slots pre-zeroed by hipMemsetAsync each launch.
// Key lesson (round 3): NEVER poll with acquire — each acquire = buffer_inv
// (whole-L2 invalidate) on gfx950. Poll RELAXED (served at coherent point),
// fence once on each side.
__device__ __forceinline__ void gridbar(unsigned* bar, int slot){
  __syncthreads();                       // drains vmcnt(0): all block stores done
  if (threadIdx.x==0){
    unsigned* cnt  = bar + (size_t)slot*64;   // 256B-strided slots
    unsigned* flag = cnt + 32;                // flag 128B away from cnt
    __builtin_amdgcn_fence(__ATOMIC_RELEASE, "agent");   // one buffer_wbl2
    unsigned old = __hip_atomic_fetch_add(cnt, 1u, __ATOMIC_RELAXED, __HIP_MEMORY_SCOPE_AGENT);
    if (old == NBLK-1u){
      __hip_atomic_store(flag, 1u, __ATOMIC_RELAXED, __HIP_MEMORY_SCOPE_AGENT);
    } else {
      while (__hip_atomic_load(flag, __ATOMIC_RELAXED, __HIP_MEMORY_SCOPE_AGENT) == 0u)
        __builtin_amdgcn_s_sleep(2);
    }
    __builtin_amdgcn_fence(__ATOMIC_ACQUIRE, "agent");   // one buffer_inv
  }
  __syncthreads();
}

// Block-wide bitonic sort of 256 u64 keys, DESCENDING. One key per thread.
__device__ __forceinline__ unsigned long long bitonic256_desc(
    unsigned long long key, int tid, unsigned long long* sbuf)
{
  #pragma unroll
  for (int k = 2; k <= 256; k <<= 1) {
    #pragma unroll
    for (int j = k >> 1; j > 0; j >>= 1) {
      unsigned long long other;
      if (j >= 64) {
        __syncthreads();
        sbuf[tid] = key;
        __syncthreads();
        other = sbuf[tid ^ j];
      } else {
        other = __shfl_xor(key, j, 64);
      }
      bool keep_max = ((tid & j) == 0) == ((tid & k) == 0);
      key = keep_max ? (key > other ? key : other)
                     : (key < other ? key : other);
    }
  }
  return key;
}

__global__ __launch_bounds__(256) void mega_kernel(
    const float* __restrict__ feat5, const float* __restrict__ feat8,
    const float* __restrict__ featcat,
    const float* __restrict__ W0, const float* __restrict__ b0v,
    const float* __restrict__ W1, const float* __restrict__ b1v,
    const float* __restrict__ W2, const float* __restrict__ b2v,
    const float* __restrict__ E0, const float* __restrict__ E1,
    const float* __restrict__ E2,
    const int* __restrict__ g0, const int* __restrict__ g1,
    unsigned* __restrict__ bar,
    float* __restrict__ P, float* __restrict__ h1buf, float* __restrict__ h2buf,
    int* __restrict__ cands1_i, float* __restrict__ gsc1,
    int* __restrict__ cands2_i, float* __restrict__ gsc2,
    float* __restrict__ o_p0, float* __restrict__ o_p1, float* __restrict__ o_p2,
    float* __restrict__ o_w1, float* __restrict__ o_w2,
    float* __restrict__ o_c1, float* __restrict__ o_c2)
{
  __shared__ __align__(16) char smem[17408];
  const int bid = blockIdx.x;
  const int tid = threadIdx.x;
  const int lane = tid & 63, wid = tid >> 6;

  // ===== Phase A: partial GEMMs.
  // bid 0..31:  feat5@W0, 2 K-splits x 16 j-tiles(32) -> P slices 0..1
  // bid 32..63: feat8@W1, same -> P slices 2..3
  // bid 64..207: featcat@W2, 18 K-splits x 8 j-tiles(64) -> P slices 4..21
  if (bid < 64) {
    const float* X = (bid < 32) ? feat5 : feat8;
    const float* W = (bid < 32) ? W0 : W1;
    int l = bid & 31;
    int split = l & 1, jt = (l >> 1) * 32;
    float* Pb = P + (size_t)((bid < 32 ? 0 : SPA) + split)*BBHH;
    int k0 = split*384;
    float (*At)[68] = (float(*)[68])smem;           // [k][row64]
    float (*Bt)[36] = (float(*)[36])(smem + 8704);  // [k][col32]
    int ti = tid >> 4, tj = tid & 15;
    float acc[4][2] = {};
    for (int ks = 0; ks < 384; ks += 32) {
      #pragma unroll
      for (int it = 0; it < 2; ++it) {
        int q = tid + it*256;
        int b = q & 63, kq = q >> 6;
        float4 v = *(const float4*)(X + (size_t)b*D0 + k0 + ks + kq*4);
        At[kq*4+0][b]=v.x; At[kq*4+1][b]=v.y; At[kq*4+2][b]=v.z; At[kq*4+3][b]=v.w;
      }
      {
        int j4 = tid & 7, kk = tid >> 3;
        float4 v = *(const float4*)(W + (size_t)(k0+ks+kk)*HH + jt + j4*4);
        *(float4*)&Bt[kk][j4*4] = v;
      }
      __syncthreads();
      #pragma unroll
      for (int k = 0; k < 32; ++k) {
        float4 a = *(const float4*)&At[k][ti*4];
        float2 b = *(const float2*)&Bt[k][tj*2];
        float av[4] = {a.x,a.y,a.z,a.w};
        float bv[2] = {b.x,b.y};
        #pragma unroll
        for (int r=0;r<4;++r)
          #pragma unroll
          for (int c=0;c<2;++c) acc[r][c] += av[r]*bv[c];
      }
      __syncthreads();
    }
    #pragma unroll
    for (int r=0;r<4;++r)
      #pragma unroll
      for (int c=0;c<2;++c)
        Pb[(size_t)(ti*4+r)*HH + jt + tj*2 + c] = acc[r][c];
  } else if (bid < 208) {
    int l = bid - 64;
    int split = l % 18, tile = l / 18;
    float* Pb = P + (size_t)(SPA+SPB+split)*BBHH;
    int k0 = split*128;
    int jt = tile*64;
    float (*At)[68] = (float(*)[68])smem;
    float (*Bt)[68] = (float(*)[68])(smem + 8704);
    int ti = tid >> 4, tj = tid & 15;
    float acc[4][4] = {};
    for (int ks = 0; ks < 128; ks += 32) {
      #pragma unroll
      for (int it = 0; it < 2; ++it) {
        int q = tid + it*256;
        int b = q & 63, kq = q >> 6;
        float4 v = *(const float4*)(featcat + (size_t)b*D2 + k0 + ks + kq*4);
        At[kq*4+0][b]=v.x; At[kq*4+1][b]=v.y; At[kq*4+2][b]=v.z; At[kq*4+3][b]=v.w;
      }
      #pragma unroll
      for (int it = 0; it < 2; ++it) {
        int q = tid + it*256;
        int j4 = q & 15, kk = q >> 4;
        float4 v = *(const float4*)(W2 + (size_t)(k0+ks+kk)*HH + jt + j4*4);
        *(float4*)&Bt[kk][j4*4] = v;
      }
      __syncthreads();
      #pragma unroll
      for (int k = 0; k < 32; ++k) {
        float4 a = *(const float4*)&At[k][ti*4];
        float4 b = *(const float4*)&Bt[k][tj*4];
        float av[4] = {a.x,a.y,a.z,a.w};
        float bv[4] = {b.x,b.y,b.z,b.w};
        #pragma unroll
        for (int r=0;r<4;++r)
          #pragma unroll
          for (int c=0;c<4;++c) acc[r][c] += av[r]*bv[c];
      }
      __syncthreads();
    }
    #pragma unroll
    for (int r=0;r<4;++r)
      #pragma unroll
      for (int c=0;c<4;++c)
        Pb[(size_t)(ti*4+r)*HH + jt + tj*4 + c] = acc[r][c];
  }

  gridbar(bar, 0);

  // ===== Phase B: level0 p0 = sigmoid(gelu(sum P0 + b0) @ E0^T), 256 blocks
  {
    int btile = bid & 1;
    int gt = bid >> 1;
    float (*At)[36] = (float(*)[36])smem;
    float (*Bt)[68] = (float(*)[68])(smem + 4608);
    int ti = tid >> 4, tj = tid & 15;
    float acc[2][4] = {};
    for (int ks = 0; ks < HH; ks += 32) {
      {
        int bb = tid & 31, kq = tid >> 5;
        float4 a = make_float4(0.f,0.f,0.f,0.f);
        #pragma unroll
        for (int s=0;s<SPA;++s){
          const float4 p = *(const float4*)(P + (size_t)s*BBHH
                             + (size_t)(btile*32+bb)*HH + ks + kq*4);
          a.x+=p.x; a.y+=p.y; a.z+=p.z; a.w+=p.w;
        }
        float4 bv = *(const float4*)(b0v + ks + kq*4);
        At[kq*4+0][bb]=geluf_(a.x+bv.x);
        At[kq*4+1][bb]=geluf_(a.y+bv.y);
        At[kq*4+2][bb]=geluf_(a.z+bv.z);
        At[kq*4+3][bb]=geluf_(a.w+bv.w);
      }
      #pragma unroll
      for (int it=0; it<2; ++it) {
        int q = tid + it*256; int g = q & 63, kq = q >> 6;
        float4 v = *(const float4*)(E0 + (size_t)(gt*64+g)*HH + ks + kq*4);
        Bt[kq*4+0][g]=v.x; Bt[kq*4+1][g]=v.y; Bt[kq*4+2][g]=v.z; Bt[kq*4+3][g]=v.w;
      }
      __syncthreads();
      #pragma unroll
      for (int k=0;k<32;++k) {
        float2 a = *(const float2*)&At[k][ti*2];
        float4 b = *(const float4*)&Bt[k][tj*4];
        float av[2] = {a.x,a.y};
        float bv[4] = {b.x,b.y,b.z,b.w};
        #pragma unroll
        for (int r=0;r<2;++r)
          #pragma unroll
          for (int c=0;c<4;++c) acc[r][c] += av[r]*bv[c];
      }
      __syncthreads();
    }
    #pragma unroll
    for (int r=0;r<2;++r)
      #pragma unroll
      for (int c=0;c<4;++c)
        o_p0[(size_t)(btile*32 + ti*2 + r)*NG0 + gt*64 + tj*4 + c] = sigmoidf_(acc[r][c]);
  }

  gridbar(bar, 1);

  // ===== Phase C: topk1 (bid<64) | h1 (64..127) | h2 (128..191)
  if (bid < 64) {
    int b = bid;
    const float* row = o_p0 + (size_t)b*NG0;
    const float4* rp = (const float4*)(row + tid*32);
    unsigned long long m = 0ull;
    #pragma unroll
    for (int t=0;t<8;++t){
      float4 v = rp[t];
      unsigned i0 = (unsigned)(tid*32 + t*4);
      m = maxu64_(m, ((unsigned long long)__float_as_uint(v.x)<<32) | (unsigned long long)(0xFFFFFFFFu-(i0+0)));
      m = maxu64_(m, ((unsigned long long)__float_as_uint(v.y)<<32) | (unsigned long long)(0xFFFFFFFFu-(i0+1)));
      m = maxu64_(m, ((unsigned long long)__float_as_uint(v.z)<<32) | (unsigned long long)(0xFFFFFFFFu-(i0+2)));
      m = maxu64_(m, ((unsigned long long)__float_as_uint(v.w)<<32) | (unsigned long long)(0xFFFFFFFFu-(i0+3)));
    }
    unsigned long long* sbuf  = (unsigned long long*)smem;
    unsigned long long* slist = (unsigned long long*)(smem + 2048);
    float* s_sc = (float*)(smem + 4096);
    int*   s_idx = (int*)(smem + 4224);
    int*   scnt = (int*)(smem + 4352);
    if (tid==0) *scnt = 0;
    __syncthreads();
    unsigned long long sk = bitonic256_desc(m, tid, sbuf);
    __syncthreads();
    sbuf[tid] = sk;
    __syncthreads();
    unsigned long long t32 = sbuf[31];
    __syncthreads();
    #pragma unroll
    for (int t=0;t<8;++t){
      float4 v = rp[t];
      unsigned i0 = (unsigned)(tid*32 + t*4);
      unsigned long long k0 = ((unsigned long long)__float_as_uint(v.x)<<32) | (unsigned long long)(0xFFFFFFFFu-(i0+0));
      unsigned long long k1 = ((unsigned long long)__float_as_uint(v.y)<<32) | (unsigned long long)(0xFFFFFFFFu-(i0+1));
      unsigned long long k2 = ((unsigned long long)__float_as_uint(v.z)<<32) | (unsigned long long)(0xFFFFFFFFu-(i0+2));
      unsigned long long k3 = ((unsigned long long)__float_as_uint(v.w)<<32) | (unsigned long long)(0xFFFFFFFFu-(i0+3));
      if (k0 >= t32) { int p = atomicAdd(scnt,1); if (p<256) slist[p]=k0; }
      if (k1 >= t32) { int p = atomicAdd(scnt,1); if (p<256) slist[p]=k1; }
      if (k2 >= t32) { int p = atomicAdd(scnt,1); if (p<256) slist[p]=k2; }
      if (k3 >= t32) { int p = atomicAdd(scnt,1); if (p<256) slist[p]=k3; }
    }
    __syncthreads();
    int cnt = *scnt;
    unsigned long long key2 = (tid < cnt) ? slist[tid] : 0ull;
    key2 = bitonic256_desc(key2, tid, sbuf);
    __syncthreads();
    sbuf[tid] = key2;
    __syncthreads();
    if (tid < TK1) {
      unsigned long long w = sbuf[tid];
      s_idx[tid] = (int)(0xFFFFFFFFu - (unsigned)(w & 0xFFFFFFFFull));
      s_sc[tid]  = __uint_as_float((unsigned)(w>>32));
    }
    __syncthreads();
    if (tid < NC1) {
      int k = tid >> 3, c = tid & 7;
      int cand = g0[(size_t)s_idx[k]*NC0 + c];
      cands1_i[(size_t)b*NC1+tid] = cand;
      gsc1[(size_t)b*NC1+tid] = s_sc[k];
      o_c1[(size_t)b*NC1+tid] = (float)cand;
    }
  } else if (bid < 128) {
    int b = bid - 64;
    int j = tid*2;
    float ax=0.f, ay=0.f;
    #pragma unroll
    for (int s=0;s<SPB;++s){
      float2 v = *(const float2*)(P + (size_t)(SPA+s)*BBHH + (size_t)b*HH + j);
      ax += v.x; ay += v.y;
    }
    float2 bv = *(const float2*)(b1v + j);
    h1buf[(size_t)b*HH + j]   = geluf_(ax + bv.x);
    h1buf[(size_t)b*HH + j+1] = geluf_(ay + bv.y);
  } else if (bid < 192) {
    int b = bid - 128;
    int j = tid*2;
    float ax=0.f, ay=0.f;
    #pragma unroll
    for (int s=0;s<SPC;++s){
      float2 v = *(const float2*)(P + (size_t)(SPA+SPB+s)*BBHH + (size_t)b*HH + j);
      ax += v.x; ay += v.y;
    }
    float2 bv = *(const float2*)(b2v + j);
    h2buf[(size_t)b*HH + j]   = geluf_(ax + bv.x);
    h2buf[(size_t)b*HH + j+1] = geluf_(ay + bv.y);
  }

  gridbar(bar, 2);

  // ===== Phase D: level1 gather-GEMV (256 blocks x 4 ytiles)
  {
    int b = bid & 63;
    const float4* h4 = (const float4*)(h1buf + (size_t)b*HH);
    float4 ha = h4[lane*2], hb = h4[lane*2+1];
    #pragma unroll
    for (int j=0;j<4;++j){
      int ytile = (bid >> 6) + 4*j;
      int cbase = ytile*16 + wid*4;
      const int* ci = cands1_i + (size_t)b*NC1 + cbase;
      int id0=ci[0], id1=ci[1], id2=ci[2], id3=ci[3];
      const float4* e0 = (const float4*)(E1 + (size_t)id0*HH);
      const float4* e1 = (const float4*)(E1 + (size_t)id1*HH);
      const float4* e2 = (const float4*)(E1 + (size_t)id2*HH);
      const float4* e3 = (const float4*)(E1 + (size_t)id3*HH);
      float4 a0=e0[lane*2], c0=e0[lane*2+1];
      float4 a1=e1[lane*2], c1=e1[lane*2+1];
      float4 a2=e2[lane*2], c2=e2[lane*2+1];
      float4 a3=e3[lane*2], c3=e3[lane*2+1];
      float s0 = ha.x*a0.x+ha.y*a0.y+ha.z*a0.z+ha.w*a0.w + hb.x*c0.x+hb.y*c0.y+hb.z*c0.z+hb.w*c0.w;
      float s1 = ha.x*a1.x+ha.y*a1.y+ha.z*a1.z+ha.w*a1.w + hb.x*c1.x+hb.y*c1.y+hb.z*c1.z+hb.w*c1.w;
      float s2 = ha.x*a2.x+ha.y*a2.y+ha.z*a2.z+ha.w*a2.w + hb.x*c2.x+hb.y*c2.y+hb.z*c2.z+hb.w*c2.w;
      float s3 = ha.x*a3.x+ha.y*a3.y+ha.z*a3.z+ha.w*a3.w + hb.x*c3.x+hb.y*c3.y+hb.z*c3.z+hb.w*c3.w;
      #pragma unroll
      for (int off=1; off<64; off<<=1) {
        s0 += __shfl_xor(s0, off);
        s1 += __shfl_xor(s1, off);
        s2 += __shfl_xor(s2, off);
        s3 += __shfl_xor(s3, off);
      }
      if (lane==0) {
        const float* gs = gsc1 + (size_t)b*NC1 + cbase;
        float p;
        p = sigmoidf_(s0); o_p1[(size_t)b*NC1+cbase+0]=p; o_w1[(size_t)b*NC1+cbase+0]=p*gs[0];
        p = sigmoidf_(s1); o_p1[(size_t)b*NC1+cbase+1]=p; o_w1[(size_t)b*NC1+cbase+1]=p*gs[1];
        p = sigmoidf_(s2); o_p1[(size_t)b*NC1+cbase+2]=p; o_w1[(size_t)b*NC1+cbase+2]=p*gs[2];
        p = sigmoidf_(s3); o_p1[(size_t)b*NC1+cbase+3]=p; o_w1[(size_t)b*NC1+cbase+3]=p*gs[3];
      }
    }
  }

  gridbar(bar, 3);

  // ===== Phase E: topk2 (blocks 0..63)
  if (bid < 64) {
    int b = bid;
    float v = o_p1[(size_t)b*NC1 + tid];
    unsigned long long key = ((unsigned long long)__float_as_uint(v)<<32) |
                             (unsigned long long)(0xFFFFFFFFu - (unsigned)tid);
    unsigned long long* sbuf = (unsigned long long*)smem;
    float* s_sc = (float*)(smem + 2048);
    int*   s_idx = (int*)(smem + 2304);
    key = bitonic256_desc(key, tid, sbuf);
    __syncthreads();
    sbuf[tid] = key;
    __syncthreads();
    if (tid < TK2) {
      unsigned long long w = sbuf[tid];
      s_idx[tid] = (int)(0xFFFFFFFFu - (unsigned)(w & 0xFFFFFFFFull));
      s_sc[tid]  = __uint_as_float((unsigned)(w>>32));
    }
    __syncthreads();
    for (int e=tid; e<NC2; e+=256) {
      int k = e/NCH1, c = e - k*NCH1;
      int meta = cands1_i[(size_t)b*NC1 + s_idx[k]];
      int cand = g1[(size_t)meta*NCH1 + c];
      cands2_i[(size_t)b*NC2+e] = cand;
      gsc2[(size_t)b*NC2+e] = s_sc[k];
      o_c2[(size_t)b*NC2+e] = (float)cand;
    }
  }

  gridbar(bar, 4);

  // ===== Phase F: level2 gather-GEMV (256 blocks x 11 ytiles)
  {
    int b = bid & 63;
    const float4* h4 = (const float4*)(h2buf + (size_t)b*HH);
    float4 ha = h4[lane*2], hb = h4[lane*2+1];
    #pragma unroll
    for (int j=0;j<11;++j){
      int ytile = (bid >> 6) + 4*j;
      int cbase = ytile*16 + wid*4;
      const int* ci = cands2_i + (size_t)b*NC2 + cbase;
      int id0=ci[0], id1=ci[1], id2=ci[2], id3=ci[3];
      const float4* e0 = (const float4*)(E2 + (size_t)id0*HH);
      const float4* e1 = (const float4*)(E2 + (size_t)id1*HH);
      const float4* e2 = (const float4*)(E2 + (size_t)id2*HH);
      const float4* e3 = (const float4*)(E2 + (size_t)id3*HH);
      float4 a0=e0[lane*2], c0=e0[lane*2+1];
      float4 a1=e1[lane*2], c1=e1[lane*2+1];
      float4 a2=e2[lane*2], c2=e2[lane*2+1];
      float4 a3=e3[lane*2], c3=e3[lane*2+1];
      float s0 = ha.x*a0.x+ha.y*a0.y+ha.z*a0.z+ha.w*a0.w + hb.x*c0.x+hb.y*c0.y+hb.z*c0.z+hb.w*c0.w;
      float s1 = ha.x*a1.x+ha.y*a1.y+ha.z*a1.z+ha.w*a1.w + hb.x*c1.x+hb.y*c1.y+hb.z*c1.z+hb.w*c1.w;
      float s2 = ha.x*a2.x+ha.y*a2.y+ha.z*a2.z+ha.w*a2.w + hb.x*c2.x+hb.y*c2.y+hb.z*c2.z+hb.w*c2.w;
      float s3 = ha.x*a3.x+ha.y*a3.y+ha.z*a3.z+ha.w*a3.w + hb.x*c3.x+hb.y*c3.y+hb.z*c3.z+hb.w*c3.w;
      #pragma unroll
      for (int off=1; off<64; off<<=1) {
        s0 += __shfl_xor(s0, off);
        s1 += __shfl_xor(s1, off);
        s2 += __shfl_xor(s2, off);
        s3 += __shfl_xor(s3, off);
      }
      if (lane==0) {
        const float* gs = gsc2 + (size_t)b*NC2 + cbase;
        float p;
        p = (s0==0.0f)?0.0f:sigmoidf_(s0); o_p2[(size_t)b*NC2+cbase+0]=p; o_w2[(size_t)b*NC2+cbase+0]=p*gs[0];
        p = (s1==0.0f)?0.0f:sigmoidf_(s1); o_p2[(size_t)b*NC2+cbase+1]=p; o_w2[(size_t)b*NC2+cbase+1]=p*gs[1];
        p = (s2==0.0f)?0.0f:sigmoidf_(s2); o_p2[(size_t)b*NC2+cbase+2]=p; o_w2[(size_t)b*NC2+cbase+2]=p*gs[2];
        p = (s3==0.0f)?0.0f:sigmoidf_(s3); o_p2[(size_t)b*NC2+cbase+3]=p; o_w2[(size_t)b*NC2+cbase+3]=p*gs[3];
      }
    }
  }
}

extern "C" void kernel_launch(void* const* d_in, const int* in_sizes, int n_in,
                              void* d_out, int out_size, void* d_ws, size_t ws_size,
                              hipStream_t stream) {
  const float* feat5   = (const float*)d_in[0];
  const float* feat8   = (const float*)d_in[1];
  const float* featcat = (const float*)d_in[2];
  const float* W0 = (const float*)d_in[3];
  const float* b0 = (const float*)d_in[4];
  const float* W1 = (const float*)d_in[5];
  const float* b1 = (const float*)d_in[6];
  const float* W2 = (const float*)d_in[7];
  const float* b2 = (const float*)d_in[8];
  const float* E0 = (const float*)d_in[9];
  const float* E1 = (const float*)d_in[10];
  const float* E2 = (const float*)d_in[11];
  const int*   g0 = (const int*)d_in[12];
  const int*   g1 = (const int*)d_in[13];

  float* out = (float*)d_out;
  float* ws  = (float*)d_ws;

  // ws layout (floats)
  size_t off = 0;
  unsigned* bar = (unsigned*)(ws);        off += 512;   // 5 slots @256B
  float* P    = ws + off; off += (size_t)NSL*BBHH;
  float* h1   = ws + off; off += BBHH;
  float* h2   = ws + off; off += BBHH;
  int*   cands1_i = (int*)(ws + off); off += (size_t)BB*NC1;
  float* gsc1 = ws + off; off += (size_t)BB*NC1;
  int*   cands2_i = (int*)(ws + off); off += (size_t)BB*NC2;
  float* gsc2 = ws + off; off += (size_t)BB*NC2;

  float* o_p0 = out;
  float* o_p1 = o_p0 + (size_t)BB*NG0;
  float* o_p2 = o_p1 + (size_t)BB*NC1;
  float* o_w1 = o_p2 + (size_t)BB*NC2;
  float* o_w2 = o_w1 + (size_t)BB*NC1;
  float* o_c1 = o_w2 + (size_t)BB*NC2;
  float* o_c2 = o_c1 + (size_t)BB*NC1;

  hipMemsetAsync(bar, 0, 2048, stream);
  mega_kernel<<<dim3(NBLK), dim3(256), 0, stream>>>(
      feat5, feat8, featcat, W0, b0, W1, b1, W2, b2, E0, E1, E2, g0, g1,
      bar, P, h1, h2, cands1_i, gsc1, cands2_i, gsc2,
      o_p0, o_p1, o_p2, o_w1, o_w2, o_c1, o_c2);
}

// Round 5
// 100.787 us; speedup vs baseline: 2.6391x; 1.4079x over previous
//
#include <hip/hip_runtime.h>
#include <math.h>

#define BB 64
#define D0 768
#define D2 2304
#define HH 512
#define BBHH (BB*HH)
#define NG0 8192
#define NC0 8
#define NCH1 11
#define TK1 32
#define TK2 64
#define NC1 (TK1*NC0)   /* 256 */
#define NC2 (TK2*NCH1)  /* 704 */
#define SPA 2    /* k-splits for h0 (768 = 2*384) */
#define SPB 2    /* k-splits for h1 */
#define SPC 18   /* k-splits for h2 (2304 = 18*128) */
#define NSL (SPA+SPB+SPC)

__device__ __forceinline__ float sigmoidf_(float x){ return 1.0f/(1.0f+expf(-x)); }
__device__ __forceinline__ float geluf_(float x){ return 0.5f*x*(1.0f+erff(x*0.70710678118654752f)); }
__device__ __forceinline__ unsigned long long maxu64_(unsigned long long a, unsigned long long b){ return a>b?a:b; }

// Block-wide bitonic sort of 256 u64 keys, DESCENDING. One key per thread.
__device__ __forceinline__ unsigned long long bitonic256_desc(
    unsigned long long key, int tid, unsigned long long* sbuf)
{
  #pragma unroll
  for (int k = 2; k <= 256; k <<= 1) {
    #pragma unroll
    for (int j = k >> 1; j > 0; j >>= 1) {
      unsigned long long other;
      if (j >= 64) {
        __syncthreads();
        sbuf[tid] = key;
        __syncthreads();
        other = sbuf[tid ^ j];
      } else {
        other = __shfl_xor(key, j, 64);
      }
      bool keep_max = ((tid & j) == 0) == ((tid & k) == 0);
      key = keep_max ? (key > other ? key : other)
                     : (key < other ? key : other);
    }
  }
  return key;
}

// ===== K1: partial GEMMs (208 blocks) =======================================
// bid 0..31:  feat5@W0, 2 K-splits x 16 j-tiles(32) -> P slices 0..1
// bid 32..63: feat8@W1, same -> P slices 2..3
// bid 64..207: featcat@W2, 18 K-splits x 8 j-tiles(64) -> P slices 4..21
__global__ __launch_bounds__(256) void gemm_h_kernel(
    const float* __restrict__ feat5, const float* __restrict__ feat8,
    const float* __restrict__ featcat,
    const float* __restrict__ W0, const float* __restrict__ W1,
    const float* __restrict__ W2, float* __restrict__ P)
{
  __shared__ __align__(16) float At[32][68];
  __shared__ __align__(16) float Bt[32][68];
  const int bid = blockIdx.x, tid = threadIdx.x;
  if (bid < 64) {
    const float* X = (bid < 32) ? feat5 : feat8;
    const float* W = (bid < 32) ? W0 : W1;
    int l = bid & 31;
    int split = l & 1, jt = (l >> 1) * 32;
    float* Pb = P + (size_t)((bid < 32 ? 0 : SPA) + split)*BBHH;
    int k0 = split*384;
    int ti = tid >> 4, tj = tid & 15;
    float acc[4][2] = {};
    for (int ks = 0; ks < 384; ks += 32) {
      #pragma unroll
      for (int it = 0; it < 2; ++it) {
        int q = tid + it*256;
        int b = q & 63, kq = q >> 6;
        float4 v = *(const float4*)(X + (size_t)b*D0 + k0 + ks + kq*4);
        At[kq*4+0][b]=v.x; At[kq*4+1][b]=v.y; At[kq*4+2][b]=v.z; At[kq*4+3][b]=v.w;
      }
      {
        int j4 = tid & 7, kk = tid >> 3;
        float4 v = *(const float4*)(W + (size_t)(k0+ks+kk)*HH + jt + j4*4);
        *(float4*)&Bt[kk][j4*4] = v;
      }
      __syncthreads();
      #pragma unroll
      for (int k = 0; k < 32; ++k) {
        float4 a = *(const float4*)&At[k][ti*4];
        float2 b = *(const float2*)&Bt[k][tj*2];
        float av[4] = {a.x,a.y,a.z,a.w};
        float bv[2] = {b.x,b.y};
        #pragma unroll
        for (int r=0;r<4;++r)
          #pragma unroll
          for (int c=0;c<2;++c) acc[r][c] += av[r]*bv[c];
      }
      __syncthreads();
    }
    #pragma unroll
    for (int r=0;r<4;++r)
      #pragma unroll
      for (int c=0;c<2;++c)
        Pb[(size_t)(ti*4+r)*HH + jt + tj*2 + c] = acc[r][c];
  } else {
    int l = bid - 64;
    int split = l % 18, tile = l / 18;
    float* Pb = P + (size_t)(SPA+SPB+split)*BBHH;
    int k0 = split*128;
    int jt = tile*64;
    int ti = tid >> 4, tj = tid & 15;
    float acc[4][4] = {};
    for (int ks = 0; ks < 128; ks += 32) {
      #pragma unroll
      for (int it = 0; it < 2; ++it) {
        int q = tid + it*256;
        int b = q & 63, kq = q >> 6;
        float4 v = *(const float4*)(featcat + (size_t)b*D2 + k0 + ks + kq*4);
        At[kq*4+0][b]=v.x; At[kq*4+1][b]=v.y; At[kq*4+2][b]=v.z; At[kq*4+3][b]=v.w;
      }
      #pragma unroll
      for (int it = 0; it < 2; ++it) {
        int q = tid + it*256;
        int j4 = q & 15, kk = q >> 4;
        float4 v = *(const float4*)(W2 + (size_t)(k0+ks+kk)*HH + jt + j4*4);
        *(float4*)&Bt[kk][j4*4] = v;
      }
      __syncthreads();
      #pragma unroll
      for (int k = 0; k < 32; ++k) {
        float4 a = *(const float4*)&At[k][ti*4];
        float4 b = *(const float4*)&Bt[k][tj*4];
        float av[4] = {a.x,a.y,a.z,a.w};
        float bv[4] = {b.x,b.y,b.z,b.w};
        #pragma unroll
        for (int r=0;r<4;++r)
          #pragma unroll
          for (int c=0;c<4;++c) acc[r][c] += av[r]*bv[c];
      }
      __syncthreads();
    }
    #pragma unroll
    for (int r=0;r<4;++r)
      #pragma unroll
      for (int c=0;c<4;++c)
        Pb[(size_t)(ti*4+r)*HH + jt + tj*4 + c] = acc[r][c];
  }
}

// ===== K2: level0 p0 = sigmoid(gelu(sum P0 + b0) @ E0^T), 256 blocks ========
__global__ __launch_bounds__(256) void level0_kernel(
    const float* __restrict__ P, const float* __restrict__ b0v,
    const float* __restrict__ E0, float* __restrict__ p0out)
{
  __shared__ __align__(16) float At[32][36];
  __shared__ __align__(16) float Bt[32][68];
  const int bid = blockIdx.x, tid = threadIdx.x;
  int btile = bid & 1;
  int gt = bid >> 1;
  int ti = tid >> 4, tj = tid & 15;
  float acc[2][4] = {};
  for (int ks = 0; ks < HH; ks += 32) {
    {
      int bb = tid & 31, kq = tid >> 5;
      float4 a = make_float4(0.f,0.f,0.f,0.f);
      #pragma unroll
      for (int s=0;s<SPA;++s){
        const float4 p = *(const float4*)(P + (size_t)s*BBHH
                           + (size_t)(btile*32+bb)*HH + ks + kq*4);
        a.x+=p.x; a.y+=p.y; a.z+=p.z; a.w+=p.w;
      }
      float4 bv = *(const float4*)(b0v + ks + kq*4);
      At[kq*4+0][bb]=geluf_(a.x+bv.x);
      At[kq*4+1][bb]=geluf_(a.y+bv.y);
      At[kq*4+2][bb]=geluf_(a.z+bv.z);
      At[kq*4+3][bb]=geluf_(a.w+bv.w);
    }
    #pragma unroll
    for (int it=0; it<2; ++it) {
      int q = tid + it*256; int g = q & 63, kq = q >> 6;
      float4 v = *(const float4*)(E0 + (size_t)(gt*64+g)*HH + ks + kq*4);
      Bt[kq*4+0][g]=v.x; Bt[kq*4+1][g]=v.y; Bt[kq*4+2][g]=v.z; Bt[kq*4+3][g]=v.w;
    }
    __syncthreads();
    #pragma unroll
    for (int k=0;k<32;++k) {
      float2 a = *(const float2*)&At[k][ti*2];
      float4 b = *(const float4*)&Bt[k][tj*4];
      float av[2] = {a.x,a.y};
      float bv[4] = {b.x,b.y,b.z,b.w};
      #pragma unroll
      for (int r=0;r<2;++r)
        #pragma unroll
        for (int c=0;c<4;++c) acc[r][c] += av[r]*bv[c];
    }
    __syncthreads();
  }
  #pragma unroll
  for (int r=0;r<2;++r)
    #pragma unroll
    for (int c=0;c<4;++c)
      p0out[(size_t)(btile*32 + ti*2 + r)*NG0 + gt*64 + tj*4 + c] = sigmoidf_(acc[r][c]);
}

// ===== K3: redundant topk1 (x4 per row) + h1-in-LDS + level1 gather =========
// 256 blocks: b = bid&63 (row), q = bid>>6 (which quarter of the 16 ytiles)
__global__ __launch_bounds__(256) void topk1_level1_kernel(
    const float* __restrict__ p0, const int* __restrict__ g0,
    const float* __restrict__ P, const float* __restrict__ b1v,
    const float* __restrict__ E1,
    int* __restrict__ cands1_i, float* __restrict__ o_c1,
    float* __restrict__ o_p1, float* __restrict__ o_w1)
{
  const int bid = blockIdx.x, tid = threadIdx.x;
  const int b = bid & 63, q = bid >> 6;
  const int lane = tid & 63, wid = tid >> 6;
  __shared__ float h1row[HH];
  __shared__ unsigned long long sbuf[256];
  __shared__ unsigned long long slist[256];
  __shared__ float s_sc[TK1];
  __shared__ int   s_idx[TK1];
  __shared__ int   scnt;
  // h1 row b -> LDS (reduce SPB split slices + bias + gelu)
  {
    int j = tid*2;
    float ax=0.f, ay=0.f;
    #pragma unroll
    for (int s=0;s<SPB;++s){
      float2 v = *(const float2*)(P + (size_t)(SPA+s)*BBHH + (size_t)b*HH + j);
      ax += v.x; ay += v.y;
    }
    float2 bv = *(const float2*)(b1v + j);
    h1row[j]   = geluf_(ax + bv.x);
    h1row[j+1] = geluf_(ay + bv.y);
  }
  if (tid==0) scnt = 0;
  // topk1: per-thread max -> sort maxima -> threshold filter -> sort survivors
  const float* row = p0 + (size_t)b*NG0;
  const float4* rp = (const float4*)(row + tid*32);
  unsigned long long m = 0ull;
  #pragma unroll
  for (int t=0;t<8;++t){
    float4 v = rp[t];
    unsigned i0 = (unsigned)(tid*32 + t*4);
    m = maxu64_(m, ((unsigned long long)__float_as_uint(v.x)<<32) | (unsigned long long)(0xFFFFFFFFu-(i0+0)));
    m = maxu64_(m, ((unsigned long long)__float_as_uint(v.y)<<32) | (unsigned long long)(0xFFFFFFFFu-(i0+1)));
    m = maxu64_(m, ((unsigned long long)__float_as_uint(v.z)<<32) | (unsigned long long)(0xFFFFFFFFu-(i0+2)));
    m = maxu64_(m, ((unsigned long long)__float_as_uint(v.w)<<32) | (unsigned long long)(0xFFFFFFFFu-(i0+3)));
  }
  __syncthreads();
  unsigned long long sk = bitonic256_desc(m, tid, sbuf);
  __syncthreads();
  sbuf[tid] = sk;
  __syncthreads();
  unsigned long long t32 = sbuf[31];
  __syncthreads();
  #pragma unroll
  for (int t=0;t<8;++t){
    float4 v = rp[t];
    unsigned i0 = (unsigned)(tid*32 + t*4);
    unsigned long long k0 = ((unsigned long long)__float_as_uint(v.x)<<32) | (unsigned long long)(0xFFFFFFFFu-(i0+0));
    unsigned long long k1 = ((unsigned long long)__float_as_uint(v.y)<<32) | (unsigned long long)(0xFFFFFFFFu-(i0+1));
    unsigned long long k2 = ((unsigned long long)__float_as_uint(v.z)<<32) | (unsigned long long)(0xFFFFFFFFu-(i0+2));
    unsigned long long k3 = ((unsigned long long)__float_as_uint(v.w)<<32) | (unsigned long long)(0xFFFFFFFFu-(i0+3));
    if (k0 >= t32) { int p = atomicAdd(&scnt,1); if (p<256) slist[p]=k0; }
    if (k1 >= t32) { int p = atomicAdd(&scnt,1); if (p<256) slist[p]=k1; }
    if (k2 >= t32) { int p = atomicAdd(&scnt,1); if (p<256) slist[p]=k2; }
    if (k3 >= t32) { int p = atomicAdd(&scnt,1); if (p<256) slist[p]=k3; }
  }
  __syncthreads();
  int cnt = scnt;
  unsigned long long key2 = (tid < cnt) ? slist[tid] : 0ull;
  key2 = bitonic256_desc(key2, tid, sbuf);
  __syncthreads();
  sbuf[tid] = key2;
  __syncthreads();
  if (tid < TK1) {
    unsigned long long w = sbuf[tid];
    s_idx[tid] = (int)(0xFFFFFFFFu - (unsigned)(w & 0xFFFFFFFFull));
    s_sc[tid]  = __uint_as_float((unsigned)(w>>32));
  }
  __syncthreads();
  // only the q==0 copy persists cands1 (needed by K4) and the c1 output
  if (q==0 && tid < NC1) {
    int k = tid >> 3, c = tid & 7;
    int cand = g0[(size_t)s_idx[k]*NC0 + c];
    cands1_i[(size_t)b*NC1+tid] = cand;
    o_c1[(size_t)b*NC1+tid] = (float)cand;
  }
  // level1 gather for ytiles q, q+4, q+8, q+12
  float4 ha = *(const float4*)&h1row[lane*8];
  float4 hb = *(const float4*)&h1row[lane*8+4];
  #pragma unroll
  for (int j=0;j<4;++j){
    int cbase = (q + 4*j)*16 + wid*4;
    int id0 = g0[(size_t)s_idx[(cbase+0)>>3]*NC0 + ((cbase+0)&7)];
    int id1 = g0[(size_t)s_idx[(cbase+1)>>3]*NC0 + ((cbase+1)&7)];
    int id2 = g0[(size_t)s_idx[(cbase+2)>>3]*NC0 + ((cbase+2)&7)];
    int id3 = g0[(size_t)s_idx[(cbase+3)>>3]*NC0 + ((cbase+3)&7)];
    const float4* pe0 = (const float4*)(E1 + (size_t)id0*HH);
    const float4* pe1 = (const float4*)(E1 + (size_t)id1*HH);
    const float4* pe2 = (const float4*)(E1 + (size_t)id2*HH);
    const float4* pe3 = (const float4*)(E1 + (size_t)id3*HH);
    float4 a0=pe0[lane*2], c0=pe0[lane*2+1];
    float4 a1=pe1[lane*2], c1=pe1[lane*2+1];
    float4 a2=pe2[lane*2], c2=pe2[lane*2+1];
    float4 a3=pe3[lane*2], c3=pe3[lane*2+1];
    float s0 = ha.x*a0.x+ha.y*a0.y+ha.z*a0.z+ha.w*a0.w + hb.x*c0.x+hb.y*c0.y+hb.z*c0.z+hb.w*c0.w;
    float s1 = ha.x*a1.x+ha.y*a1.y+ha.z*a1.z+ha.w*a1.w + hb.x*c1.x+hb.y*c1.y+hb.z*c1.z+hb.w*c1.w;
    float s2 = ha.x*a2.x+ha.y*a2.y+ha.z*a2.z+ha.w*a2.w + hb.x*c2.x+hb.y*c2.y+hb.z*c2.z+hb.w*c2.w;
    float s3 = ha.x*a3.x+ha.y*a3.y+ha.z*a3.z+ha.w*a3.w + hb.x*c3.x+hb.y*c3.y+hb.z*c3.z+hb.w*c3.w;
    #pragma unroll
    for (int off=1; off<64; off<<=1) {
      s0 += __shfl_xor(s0, off);
      s1 += __shfl_xor(s1, off);
      s2 += __shfl_xor(s2, off);
      s3 += __shfl_xor(s3, off);
    }
    if (lane==0) {
      float p;
      p = sigmoidf_(s0); o_p1[(size_t)b*NC1+cbase+0]=p; o_w1[(size_t)b*NC1+cbase+0]=p*s_sc[(cbase+0)>>3];
      p = sigmoidf_(s1); o_p1[(size_t)b*NC1+cbase+1]=p; o_w1[(size_t)b*NC1+cbase+1]=p*s_sc[(cbase+1)>>3];
      p = sigmoidf_(s2); o_p1[(size_t)b*NC1+cbase+2]=p; o_w1[(size_t)b*NC1+cbase+2]=p*s_sc[(cbase+2)>>3];
      p = sigmoidf_(s3); o_p1[(size_t)b*NC1+cbase+3]=p; o_w1[(size_t)b*NC1+cbase+3]=p*s_sc[(cbase+3)>>3];
    }
  }
}

// ===== K4: redundant topk2 (x4 per row) + h2-in-LDS + level2 gather =========
// 256 blocks: b = bid&63 (row), q = bid>>6 (quarter of the 44 ytiles)
__global__ __launch_bounds__(256) void topk2_level2_kernel(
    const float* __restrict__ p1, const int* __restrict__ cands1_i,
    const int* __restrict__ g1,
    const float* __restrict__ P, const float* __restrict__ b2v,
    const float* __restrict__ E2,
    float* __restrict__ o_c2, float* __restrict__ o_p2, float* __restrict__ o_w2)
{
  const int bid = blockIdx.x, tid = threadIdx.x;
  const int b = bid & 63, q = bid >> 6;
  const int lane = tid & 63, wid = tid >> 6;
  __shared__ float h2row[HH];
  __shared__ unsigned long long sbuf[256];
  __shared__ float s_sc[TK2];
  __shared__ int   s_idx[TK2];
  __shared__ int   c1row[NC1];
  // h2 row b -> LDS (reduce SPC split slices + bias + gelu)
  {
    int j = tid*2;
    float ax=0.f, ay=0.f;
    #pragma unroll
    for (int s=0;s<SPC;++s){
      float2 v = *(const float2*)(P + (size_t)(SPA+SPB+s)*BBHH + (size_t)b*HH + j);
      ax += v.x; ay += v.y;
    }
    float2 bv = *(const float2*)(b2v + j);
    h2row[j]   = geluf_(ax + bv.x);
    h2row[j+1] = geluf_(ay + bv.y);
  }
  c1row[tid] = cands1_i[(size_t)b*NC1 + tid];
  float v = p1[(size_t)b*NC1 + tid];
  unsigned long long key = ((unsigned long long)__float_as_uint(v)<<32) |
                           (unsigned long long)(0xFFFFFFFFu - (unsigned)tid);
  __syncthreads();
  key = bitonic256_desc(key, tid, sbuf);
  __syncthreads();
  sbuf[tid] = key;
  __syncthreads();
  if (tid < TK2) {
    unsigned long long w = sbuf[tid];
    s_idx[tid] = (int)(0xFFFFFFFFu - (unsigned)(w & 0xFFFFFFFFull));
    s_sc[tid]  = __uint_as_float((unsigned)(w>>32));
  }
  __syncthreads();
  if (q==0) {
    for (int e=tid; e<NC2; e+=256) {
      int k = e/NCH1, c = e - k*NCH1;
      int meta = c1row[s_idx[k]];
      int cand = g1[(size_t)meta*NCH1 + c];
      o_c2[(size_t)b*NC2+e] = (float)cand;
    }
  }
  // level2 gather for ytiles q+4j, j=0..10
  float4 ha = *(const float4*)&h2row[lane*8];
  float4 hb = *(const float4*)&h2row[lane*8+4];
  #pragma unroll
  for (int j=0;j<11;++j){
    int cbase = (q + 4*j)*16 + wid*4;
    int k0i = (cbase+0)/NCH1, c0i = (cbase+0) - k0i*NCH1;
    int k1i = (cbase+1)/NCH1, c1i = (cbase+1) - k1i*NCH1;
    int k2i = (cbase+2)/NCH1, c2i = (cbase+2) - k2i*NCH1;
    int k3i = (cbase+3)/NCH1, c3i = (cbase+3) - k3i*NCH1;
    int id0 = g1[(size_t)c1row[s_idx[k0i]]*NCH1 + c0i];
    int id1 = g1[(size_t)c1row[s_idx[k1i]]*NCH1 + c1i];
    int id2 = g1[(size_t)c1row[s_idx[k2i]]*NCH1 + c2i];
    int id3 = g1[(size_t)c1row[s_idx[k3i]]*NCH1 + c3i];
    const float4* pe0 = (const float4*)(E2 + (size_t)id0*HH);
    const float4* pe1 = (const float4*)(E2 + (size_t)id1*HH);
    const float4* pe2 = (const float4*)(E2 + (size_t)id2*HH);
    const float4* pe3 = (const float4*)(E2 + (size_t)id3*HH);
    float4 a0=pe0[lane*2], c0=pe0[lane*2+1];
    float4 a1=pe1[lane*2], c1=pe1[lane*2+1];
    float4 a2=pe2[lane*2], c2=pe2[lane*2+1];
    float4 a3=pe3[lane*2], c3=pe3[lane*2+1];
    float s0 = ha.x*a0.x+ha.y*a0.y+ha.z*a0.z+ha.w*a0.w + hb.x*c0.x+hb.y*c0.y+hb.z*c0.z+hb.w*c0.w;
    float s1 = ha.x*a1.x+ha.y*a1.y+ha.z*a1.z+ha.w*a1.w + hb.x*c1.x+hb.y*c1.y+hb.z*c1.z+hb.w*c1.w;
    float s2 = ha.x*a2.x+ha.y*a2.y+ha.z*a2.z+ha.w*a2.w + hb.x*c2.x+hb.y*c2.y+hb.z*c2.z+hb.w*c2.w;
    float s3 = ha.x*a3.x+ha.y*a3.y+ha.z*a3.z+ha.w*a3.w + hb.x*c3.x+hb.y*c3.y+hb.z*c3.z+hb.w*c3.w;
    #pragma unroll
    for (int off=1; off<64; off<<=1) {
      s0 += __shfl_xor(s0, off);
      s1 += __shfl_xor(s1, off);
      s2 += __shfl_xor(s2, off);
      s3 += __shfl_xor(s3, off);
    }
    if (lane==0) {
      float p;
      p = (s0==0.0f)?0.0f:sigmoidf_(s0); o_p2[(size_t)b*NC2+cbase+0]=p; o_w2[(size_t)b*NC2+cbase+0]=p*s_sc[k0i];
      p = (s1==0.0f)?0.0f:sigmoidf_(s1); o_p2[(size_t)b*NC2+cbase+1]=p; o_w2[(size_t)b*NC2+cbase+1]=p*s_sc[k1i];
      p = (s2==0.0f)?0.0f:sigmoidf_(s2); o_p2[(size_t)b*NC2+cbase+2]=p; o_w2[(size_t)b*NC2+cbase+2]=p*s_sc[k2i];
      p = (s3==0.0f)?0.0f:sigmoidf_(s3); o_p2[(size_t)b*NC2+cbase+3]=p; o_w2[(size_t)b*NC2+cbase+3]=p*s_sc[k3i];
    }
  }
}

extern "C" void kernel_launch(void* const* d_in, const int* in_sizes, int n_in,
                              void* d_out, int out_size, void* d_ws, size_t ws_size,
                              hipStream_t stream) {
  const float* feat5   = (const float*)d_in[0];
  const float* feat8   = (const float*)d_in[1];
  const float* featcat = (const float*)d_in[2];
  const float* W0 = (const float*)d_in[3];
  const float* b0 = (const float*)d_in[4];
  const float* W1 = (const float*)d_in[5];
  const float* b1 = (const float*)d_in[6];
  const float* W2 = (const float*)d_in[7];
  const float* b2 = (const float*)d_in[8];
  const float* E0 = (const float*)d_in[9];
  const float* E1 = (const float*)d_in[10];
  const float* E2 = (const float*)d_in[11];
  const int*   g0 = (const int*)d_in[12];
  const int*   g1 = (const int*)d_in[13];

  float* out = (float*)d_out;
  float* ws  = (float*)d_ws;

  size_t off = 0;
  float* P = ws + off; off += (size_t)NSL*BBHH;
  int*   cands1_i = (int*)(ws + off); off += (size_t)BB*NC1;

  float* o_p0 = out;
  float* o_p1 = o_p0 + (size_t)BB*NG0;
  float* o_p2 = o_p1 + (size_t)BB*NC1;
  float* o_w1 = o_p2 + (size_t)BB*NC2;
  float* o_w2 = o_w1 + (size_t)BB*NC1;
  float* o_c1 = o_w2 + (size_t)BB*NC2;
  float* o_c2 = o_c1 + (size_t)BB*NC1;

  gemm_h_kernel<<<dim3(208), dim3(256), 0, stream>>>(feat5, feat8, featcat, W0, W1, W2, P);
  level0_kernel<<<dim3(256), dim3(256), 0, stream>>>(P, b0, E0, o_p0);
  topk1_level1_kernel<<<dim3(256), dim3(256), 0, stream>>>(o_p0, g0, P, b1, E1,
      cands1_i, o_c1, o_p1, o_w1);
  topk2_level2_kernel<<<dim3(256), dim3(256), 0, stream>>>(o_p1, cands1_i, g1, P, b2, E2,
      o_c2, o_p2, o_w2);
}

// Round 6
// 90.048 us; speedup vs baseline: 2.9538x; 1.1192x over previous
//
#include <hip/hip_runtime.h>
#include <math.h>

#define BB 64
#define D0 768
#define D2 2304
#define HH 512
#define BBHH (BB*HH)
#define NG0 8192
#define NC0 8
#define NCH1 11
#define TK1 32
#define TK2 64
#define NC1 (TK1*NC0)   /* 256 */
#define NC2 (TK2*NCH1)  /* 704 */
#define SPA 2    /* k-splits for h0 (768 = 2*384) */
#define SPB 2    /* k-splits for h1 */
#define SPC 6    /* k-splits for h2 (2304 = 6*384) */
#define NSL (SPA+SPB+SPC)   /* 10 */

__device__ __forceinline__ float sigmoidf_(float x){ return 1.0f/(1.0f+expf(-x)); }
__device__ __forceinline__ float geluf_(float x){ return 0.5f*x*(1.0f+erff(x*0.70710678118654752f)); }
__device__ __forceinline__ unsigned long long maxu64_(unsigned long long a, unsigned long long b){ return a>b?a:b; }

// Block-wide bitonic sort of 256 u64 keys, DESCENDING. One key per thread.
__device__ __forceinline__ unsigned long long bitonic256_desc(
    unsigned long long key, int tid, unsigned long long* sbuf)
{
  #pragma unroll
  for (int k = 2; k <= 256; k <<= 1) {
    #pragma unroll
    for (int j = k >> 1; j > 0; j >>= 1) {
      unsigned long long other;
      if (j >= 64) {
        __syncthreads();
        sbuf[tid] = key;
        __syncthreads();
        other = sbuf[tid ^ j];
      } else {
        other = __shfl_xor(key, j, 64);
      }
      bool keep_max = ((tid & j) == 0) == ((tid & k) == 0);
      key = keep_max ? (key > other ? key : other)
                     : (key < other ? key : other);
    }
  }
  return key;
}

// ===== K1: partial GEMMs (160 blocks), K-chunks of 384 ======================
// bid 0..31:  feat5@W0 -> slices 0..1   (split=l&1, jt=(l>>1)*32)
// bid 32..63: feat8@W1 -> slices 2..3
// bid 64..159: featcat@W2 -> slices 4..9 (split=l%6, jt=(l/6)*32)
__global__ __launch_bounds__(256) void gemm_h_kernel(
    const float* __restrict__ feat5, const float* __restrict__ feat8,
    const float* __restrict__ featcat,
    const float* __restrict__ W0, const float* __restrict__ W1,
    const float* __restrict__ W2, float* __restrict__ P)
{
  __shared__ __align__(16) float At[32][68];
  __shared__ __align__(16) float Bt[32][36];
  const int bid = blockIdx.x, tid = threadIdx.x;
  const float* X; const float* W; int Dm, split, jt, slice;
  if (bid < 32)      { X=feat5;   W=W0; Dm=D0; int l=bid;    split=l&1; jt=(l>>1)*32; slice=split; }
  else if (bid < 64) { X=feat8;   W=W1; Dm=D0; int l=bid-32; split=l&1; jt=(l>>1)*32; slice=SPA+split; }
  else               { X=featcat; W=W2; Dm=D2; int l=bid-64; split=l%6; jt=(l/6)*32;  slice=SPA+SPB+split; }
  float* Pb = P + (size_t)slice*BBHH;
  int k0 = split*384;
  int ti = tid >> 4, tj = tid & 15;
  float acc[4][2] = {};
  for (int ks = 0; ks < 384; ks += 32) {
    #pragma unroll
    for (int it = 0; it < 2; ++it) {             // A: 64 rows x 32 k
      int q = tid + it*256;
      int b = q & 63, kq = q >> 6;
      float4 v = *(const float4*)(X + (size_t)b*Dm + k0 + ks + kq*4);
      At[kq*4+0][b]=v.x; At[kq*4+1][b]=v.y; At[kq*4+2][b]=v.z; At[kq*4+3][b]=v.w;
    }
    {                                            // B: 32 k x 32 cols
      int j4 = tid & 7, kk = tid >> 3;
      float4 v = *(const float4*)(W + (size_t)(k0+ks+kk)*HH + jt + j4*4);
      *(float4*)&Bt[kk][j4*4] = v;
    }
    __syncthreads();
    #pragma unroll
    for (int k = 0; k < 32; ++k) {
      float4 a = *(const float4*)&At[k][ti*4];
      float2 b = *(const float2*)&Bt[k][tj*2];
      float av[4] = {a.x,a.y,a.z,a.w};
      float bv[2] = {b.x,b.y};
      #pragma unroll
      for (int r=0;r<4;++r)
        #pragma unroll
        for (int c=0;c<2;++c) acc[r][c] += av[r]*bv[c];
    }
    __syncthreads();
  }
  #pragma unroll
  for (int r=0;r<4;++r)
    #pragma unroll
    for (int c=0;c<2;++c)
      Pb[(size_t)(ti*4+r)*HH + jt + tj*2 + c] = acc[r][c];
}

// ===== K2: level0, 512 blocks (2/CU): 16 b-rows x 64 g-cols per block =======
__global__ __launch_bounds__(256,2) void level0_kernel(
    const float* __restrict__ P, const float* __restrict__ b0v,
    const float* __restrict__ E0, float* __restrict__ p0out)
{
  __shared__ __align__(16) float At[32][20];   // [k][row16]
  __shared__ __align__(16) float Bt[32][68];   // [k][g64]
  const int bid = blockIdx.x, tid = threadIdx.x;
  const int btile = bid & 3;        // 16-row slab
  const int gt = bid >> 2;          // 0..127, 64 g-cols
  const int ti = tid >> 4, tj = tid & 15;
  float acc[4] = {};
  for (int ks = 0; ks < HH; ks += 32) {
    {
      int bb = tid & 15, kq = tid >> 4;        // kq 0..15 (2 k each)
      float2 a = make_float2(0.f, 0.f);
      #pragma unroll
      for (int s=0;s<SPA;++s){
        float2 p = *(const float2*)(P + (size_t)s*BBHH
                        + (size_t)(btile*16+bb)*HH + ks + kq*2);
        a.x += p.x; a.y += p.y;
      }
      float2 bv = *(const float2*)(b0v + ks + kq*2);
      At[kq*2+0][bb] = geluf_(a.x + bv.x);
      At[kq*2+1][bb] = geluf_(a.y + bv.y);
    }
    #pragma unroll
    for (int it=0; it<2; ++it) {
      int q = tid + it*256; int g = q & 63, kq = q >> 6;
      float4 v = *(const float4*)(E0 + (size_t)(gt*64+g)*HH + ks + kq*4);
      Bt[kq*4+0][g]=v.x; Bt[kq*4+1][g]=v.y; Bt[kq*4+2][g]=v.z; Bt[kq*4+3][g]=v.w;
    }
    __syncthreads();
    #pragma unroll
    for (int k=0;k<32;++k) {
      float a = At[k][ti];                 // broadcast within 16-lane groups
      float4 b = *(const float4*)&Bt[k][tj*4];
      acc[0] += a*b.x; acc[1] += a*b.y; acc[2] += a*b.z; acc[3] += a*b.w;
    }
    __syncthreads();
  }
  #pragma unroll
  for (int c=0;c<4;++c)
    p0out[(size_t)(btile*16 + ti)*NG0 + gt*64 + tj*4 + c] = sigmoidf_(acc[c]);
}

// ===== K3: redundant topk1 (x4 per row) + h1-in-LDS + level1 gather =========
// 256 blocks: b = bid&63 (row), q = bid>>6 (quarter of the 16 ytiles)
__global__ __launch_bounds__(256) void topk1_level1_kernel(
    const float* __restrict__ p0, const int* __restrict__ g0,
    const float* __restrict__ P, const float* __restrict__ b1v,
    const float* __restrict__ E1,
    int* __restrict__ cands1_i, float* __restrict__ o_c1,
    float* __restrict__ o_p1, float* __restrict__ o_w1)
{
  const int bid = blockIdx.x, tid = threadIdx.x;
  const int b = bid & 63, q = bid >> 6;
  const int lane = tid & 63, wid = tid >> 6;
  __shared__ float h1row[HH];
  __shared__ unsigned long long sbuf[256];
  __shared__ unsigned long long slist[256];
  __shared__ float s_sc[TK1];
  __shared__ int   s_idx[TK1];
  __shared__ int   scnt;
  {
    int j = tid*2;
    float ax=0.f, ay=0.f;
    #pragma unroll
    for (int s=0;s<SPB;++s){
      float2 v = *(const float2*)(P + (size_t)(SPA+s)*BBHH + (size_t)b*HH + j);
      ax += v.x; ay += v.y;
    }
    float2 bv = *(const float2*)(b1v + j);
    h1row[j]   = geluf_(ax + bv.x);
    h1row[j+1] = geluf_(ay + bv.y);
  }
  if (tid==0) scnt = 0;
  const float* row = p0 + (size_t)b*NG0;
  const float4* rp = (const float4*)(row + tid*32);
  unsigned long long m = 0ull;
  #pragma unroll
  for (int t=0;t<8;++t){
    float4 v = rp[t];
    unsigned i0 = (unsigned)(tid*32 + t*4);
    m = maxu64_(m, ((unsigned long long)__float_as_uint(v.x)<<32) | (unsigned long long)(0xFFFFFFFFu-(i0+0)));
    m = maxu64_(m, ((unsigned long long)__float_as_uint(v.y)<<32) | (unsigned long long)(0xFFFFFFFFu-(i0+1)));
    m = maxu64_(m, ((unsigned long long)__float_as_uint(v.z)<<32) | (unsigned long long)(0xFFFFFFFFu-(i0+2)));
    m = maxu64_(m, ((unsigned long long)__float_as_uint(v.w)<<32) | (unsigned long long)(0xFFFFFFFFu-(i0+3)));
  }
  __syncthreads();
  unsigned long long sk = bitonic256_desc(m, tid, sbuf);
  __syncthreads();
  sbuf[tid] = sk;
  __syncthreads();
  unsigned long long t32 = sbuf[31];
  __syncthreads();
  #pragma unroll
  for (int t=0;t<8;++t){
    float4 v = rp[t];
    unsigned i0 = (unsigned)(tid*32 + t*4);
    unsigned long long k0 = ((unsigned long long)__float_as_uint(v.x)<<32) | (unsigned long long)(0xFFFFFFFFu-(i0+0));
    unsigned long long k1 = ((unsigned long long)__float_as_uint(v.y)<<32) | (unsigned long long)(0xFFFFFFFFu-(i0+1));
    unsigned long long k2 = ((unsigned long long)__float_as_uint(v.z)<<32) | (unsigned long long)(0xFFFFFFFFu-(i0+2));
    unsigned long long k3 = ((unsigned long long)__float_as_uint(v.w)<<32) | (unsigned long long)(0xFFFFFFFFu-(i0+3));
    if (k0 >= t32) { int p = atomicAdd(&scnt,1); if (p<256) slist[p]=k0; }
    if (k1 >= t32) { int p = atomicAdd(&scnt,1); if (p<256) slist[p]=k1; }
    if (k2 >= t32) { int p = atomicAdd(&scnt,1); if (p<256) slist[p]=k2; }
    if (k3 >= t32) { int p = atomicAdd(&scnt,1); if (p<256) slist[p]=k3; }
  }
  __syncthreads();
  int cnt = scnt;
  unsigned long long key2 = (tid < cnt) ? slist[tid] : 0ull;
  key2 = bitonic256_desc(key2, tid, sbuf);
  __syncthreads();
  sbuf[tid] = key2;
  __syncthreads();
  if (tid < TK1) {
    unsigned long long w = sbuf[tid];
    s_idx[tid] = (int)(0xFFFFFFFFu - (unsigned)(w & 0xFFFFFFFFull));
    s_sc[tid]  = __uint_as_float((unsigned)(w>>32));
  }
  __syncthreads();
  if (q==0 && tid < NC1) {
    int k = tid >> 3, c = tid & 7;
    int cand = g0[(size_t)s_idx[k]*NC0 + c];
    cands1_i[(size_t)b*NC1+tid] = cand;
    o_c1[(size_t)b*NC1+tid] = (float)cand;
  }
  float4 ha = *(const float4*)&h1row[lane*8];
  float4 hb = *(const float4*)&h1row[lane*8+4];
  #pragma unroll
  for (int j=0;j<4;++j){
    int cbase = (q + 4*j)*16 + wid*4;
    int id0 = g0[(size_t)s_idx[(cbase+0)>>3]*NC0 + ((cbase+0)&7)];
    int id1 = g0[(size_t)s_idx[(cbase+1)>>3]*NC0 + ((cbase+1)&7)];
    int id2 = g0[(size_t)s_idx[(cbase+2)>>3]*NC0 + ((cbase+2)&7)];
    int id3 = g0[(size_t)s_idx[(cbase+3)>>3]*NC0 + ((cbase+3)&7)];
    const float4* pe0 = (const float4*)(E1 + (size_t)id0*HH);
    const float4* pe1 = (const float4*)(E1 + (size_t)id1*HH);
    const float4* pe2 = (const float4*)(E1 + (size_t)id2*HH);
    const float4* pe3 = (const float4*)(E1 + (size_t)id3*HH);
    float4 a0=pe0[lane*2], c0=pe0[lane*2+1];
    float4 a1=pe1[lane*2], c1=pe1[lane*2+1];
    float4 a2=pe2[lane*2], c2=pe2[lane*2+1];
    float4 a3=pe3[lane*2], c3=pe3[lane*2+1];
    float s0 = ha.x*a0.x+ha.y*a0.y+ha.z*a0.z+ha.w*a0.w + hb.x*c0.x+hb.y*c0.y+hb.z*c0.z+hb.w*c0.w;
    float s1 = ha.x*a1.x+ha.y*a1.y+ha.z*a1.z+ha.w*a1.w + hb.x*c1.x+hb.y*c1.y+hb.z*c1.z+hb.w*c1.w;
    float s2 = ha.x*a2.x+ha.y*a2.y+ha.z*a2.z+ha.w*a2.w + hb.x*c2.x+hb.y*c2.y+hb.z*c2.z+hb.w*c2.w;
    float s3 = ha.x*a3.x+ha.y*a3.y+ha.z*a3.z+ha.w*a3.w + hb.x*c3.x+hb.y*c3.y+hb.z*c3.z+hb.w*c3.w;
    #pragma unroll
    for (int off=1; off<64; off<<=1) {
      s0 += __shfl_xor(s0, off);
      s1 += __shfl_xor(s1, off);
      s2 += __shfl_xor(s2, off);
      s3 += __shfl_xor(s3, off);
    }
    if (lane==0) {
      float p;
      p = sigmoidf_(s0); o_p1[(size_t)b*NC1+cbase+0]=p; o_w1[(size_t)b*NC1+cbase+0]=p*s_sc[(cbase+0)>>3];
      p = sigmoidf_(s1); o_p1[(size_t)b*NC1+cbase+1]=p; o_w1[(size_t)b*NC1+cbase+1]=p*s_sc[(cbase+1)>>3];
      p = sigmoidf_(s2); o_p1[(size_t)b*NC1+cbase+2]=p; o_w1[(size_t)b*NC1+cbase+2]=p*s_sc[(cbase+2)>>3];
      p = sigmoidf_(s3); o_p1[(size_t)b*NC1+cbase+3]=p; o_w1[(size_t)b*NC1+cbase+3]=p*s_sc[(cbase+3)>>3];
    }
  }
}

// ===== K4: redundant topk2 (x8 per row) + h2-in-LDS + level2 gather =========
// 512 blocks (2/CU): b = bid&63 (row), q = bid>>6 (eighth of the 704 cands)
__global__ __launch_bounds__(256,2) void topk2_level2_kernel(
    const float* __restrict__ p1, const int* __restrict__ cands1_i,
    const int* __restrict__ g1,
    const float* __restrict__ P, const float* __restrict__ b2v,
    const float* __restrict__ E2,
    float* __restrict__ o_c2, float* __restrict__ o_p2, float* __restrict__ o_w2)
{
  const int bid = blockIdx.x, tid = threadIdx.x;
  const int b = bid & 63, q = bid >> 6;     // q 0..7
  const int lane = tid & 63, wid = tid >> 6;
  __shared__ float h2row[HH];
  __shared__ unsigned long long sbuf[256];
  __shared__ float s_sc[TK2];
  __shared__ int   s_idx[TK2];
  __shared__ int   c1row[NC1];
  {
    int j = tid*2;
    float ax=0.f, ay=0.f;
    #pragma unroll
    for (int s=0;s<SPC;++s){
      float2 v = *(const float2*)(P + (size_t)(SPA+SPB+s)*BBHH + (size_t)b*HH + j);
      ax += v.x; ay += v.y;
    }
    float2 bv = *(const float2*)(b2v + j);
    h2row[j]   = geluf_(ax + bv.x);
    h2row[j+1] = geluf_(ay + bv.y);
  }
  c1row[tid] = cands1_i[(size_t)b*NC1 + tid];
  float v = p1[(size_t)b*NC1 + tid];
  unsigned long long key = ((unsigned long long)__float_as_uint(v)<<32) |
                           (unsigned long long)(0xFFFFFFFFu - (unsigned)tid);
  __syncthreads();
  key = bitonic256_desc(key, tid, sbuf);
  __syncthreads();
  sbuf[tid] = key;
  __syncthreads();
  if (tid < TK2) {
    unsigned long long w = sbuf[tid];
    s_idx[tid] = (int)(0xFFFFFFFFu - (unsigned)(w & 0xFFFFFFFFull));
    s_sc[tid]  = __uint_as_float((unsigned)(w>>32));
  }
  __syncthreads();
  if (q==0) {
    for (int e=tid; e<NC2; e+=256) {
      int k = e/NCH1, c = e - k*NCH1;
      int meta = c1row[s_idx[k]];
      int cand = g1[(size_t)meta*NCH1 + c];
      o_c2[(size_t)b*NC2+e] = (float)cand;
    }
  }
  // gather: 88 cands per block = 11 iters x 4 waves x 2 cands
  float4 ha = *(const float4*)&h2row[lane*8];
  float4 hb = *(const float4*)&h2row[lane*8+4];
  for (int j=0;j<11;++j){
    int cbase = q*88 + j*8 + wid*2;
    int k0i = (cbase+0)/NCH1, c0i = (cbase+0) - k0i*NCH1;
    int k1i = (cbase+1)/NCH1, c1i = (cbase+1) - k1i*NCH1;
    int id0 = g1[(size_t)c1row[s_idx[k0i]]*NCH1 + c0i];
    int id1 = g1[(size_t)c1row[s_idx[k1i]]*NCH1 + c1i];
    const float4* pe0 = (const float4*)(E2 + (size_t)id0*HH);
    const float4* pe1 = (const float4*)(E2 + (size_t)id1*HH);
    float4 a0=pe0[lane*2], c0=pe0[lane*2+1];
    float4 a1=pe1[lane*2], c1=pe1[lane*2+1];
    float s0 = ha.x*a0.x+ha.y*a0.y+ha.z*a0.z+ha.w*a0.w + hb.x*c0.x+hb.y*c0.y+hb.z*c0.z+hb.w*c0.w;
    float s1 = ha.x*a1.x+ha.y*a1.y+ha.z*a1.z+ha.w*a1.w + hb.x*c1.x+hb.y*c1.y+hb.z*c1.z+hb.w*c1.w;
    #pragma unroll
    for (int off=1; off<64; off<<=1) {
      s0 += __shfl_xor(s0, off);
      s1 += __shfl_xor(s1, off);
    }
    if (lane==0) {
      float p;
      p = (s0==0.0f)?0.0f:sigmoidf_(s0); o_p2[(size_t)b*NC2+cbase+0]=p; o_w2[(size_t)b*NC2+cbase+0]=p*s_sc[k0i];
      p = (s1==0.0f)?0.0f:sigmoidf_(s1); o_p2[(size_t)b*NC2+cbase+1]=p; o_w2[(size_t)b*NC2+cbase+1]=p*s_sc[k1i];
    }
  }
}

extern "C" void kernel_launch(void* const* d_in, const int* in_sizes, int n_in,
                              void* d_out, int out_size, void* d_ws, size_t ws_size,
                              hipStream_t stream) {
  const float* feat5   = (const float*)d_in[0];
  const float* feat8   = (const float*)d_in[1];
  const float* featcat = (const float*)d_in[2];
  const float* W0 = (const float*)d_in[3];
  const float* b0 = (const float*)d_in[4];
  const float* W1 = (const float*)d_in[5];
  const float* b1 = (const float*)d_in[6];
  const float* W2 = (const float*)d_in[7];
  const float* b2 = (const float*)d_in[8];
  const float* E0 = (const float*)d_in[9];
  const float* E1 = (const float*)d_in[10];
  const float* E2 = (const float*)d_in[11];
  const int*   g0 = (const int*)d_in[12];
  const int*   g1 = (const int*)d_in[13];

  float* out = (float*)d_out;
  float* ws  = (float*)d_ws;

  size_t off = 0;
  float* P = ws + off; off += (size_t)NSL*BBHH;
  int*   cands1_i = (int*)(ws + off); off += (size_t)BB*NC1;

  float* o_p0 = out;
  float* o_p1 = o_p0 + (size_t)BB*NG0;
  float* o_p2 = o_p1 + (size_t)BB*NC1;
  float* o_w1 = o_p2 + (size_t)BB*NC2;
  float* o_w2 = o_w1 + (size_t)BB*NC1;
  float* o_c1 = o_w2 + (size_t)BB*NC2;
  float* o_c2 = o_c1 + (size_t)BB*NC1;

  gemm_h_kernel<<<dim3(160), dim3(256), 0, stream>>>(feat5, feat8, featcat, W0, W1, W2, P);
  level0_kernel<<<dim3(512), dim3(256), 0, stream>>>(P, b0, E0, o_p0);
  topk1_level1_kernel<<<dim3(256), dim3(256), 0, stream>>>(o_p0, g0, P, b1, E1,
      cands1_i, o_c1, o_p1, o_w1);
  topk2_level2_kernel<<<dim3(512), dim3(256), 0, stream>>>(o_p1, cands1_i, g1, P, b2, E2,
      o_c2, o_p2, o_w2);
}

// Round 7
// 88.509 us; speedup vs baseline: 3.0052x; 1.0174x over previous
//
#include <hip/hip_runtime.h>
#include <math.h>

#define BB 64
#define D0 768
#define D2 2304
#define HH 512
#define BBHH (BB*HH)
#define NG0 8192
#define NC0 8
#define NCH1 11
#define TK1 32
#define TK2 64
#define NC1 (TK1*NC0)   /* 256 */
#define NC2 (TK2*NCH1)  /* 704 */
#define SPA 2    /* k-splits for h0 (768 = 2*384) */
#define SPB 2    /* k-splits for h1 */
#define SPC 6    /* k-splits for h2 (2304 = 6*384) */
#define NSL (SPA+SPB+SPC)   /* 10 */

__device__ __forceinline__ float sigmoidf_(float x){ return 1.0f/(1.0f+expf(-x)); }
__device__ __forceinline__ float geluf_(float x){ return 0.5f*x*(1.0f+erff(x*0.70710678118654752f)); }
__device__ __forceinline__ unsigned long long maxu64_(unsigned long long a, unsigned long long b){ return a>b?a:b; }
__device__ __forceinline__ float dot8_(float4 ha, float4 hb, float4 a, float4 c){
  return ha.x*a.x+ha.y*a.y+ha.z*a.z+ha.w*a.w + hb.x*c.x+hb.y*c.y+hb.z*c.z+hb.w*c.w;
}

// Block-wide bitonic sort of 256 u64 keys, DESCENDING. One key per thread.
__device__ __forceinline__ unsigned long long bitonic256_desc(
    unsigned long long key, int tid, unsigned long long* sbuf)
{
  #pragma unroll
  for (int k = 2; k <= 256; k <<= 1) {
    #pragma unroll
    for (int j = k >> 1; j > 0; j >>= 1) {
      unsigned long long other;
      if (j >= 64) {
        __syncthreads();
        sbuf[tid] = key;
        __syncthreads();
        other = sbuf[tid ^ j];
      } else {
        other = __shfl_xor(key, j, 64);
      }
      bool keep_max = ((tid & j) == 0) == ((tid & k) == 0);
      key = keep_max ? (key > other ? key : other)
                     : (key < other ? key : other);
    }
  }
  return key;
}

// ===== K1: partial GEMMs (160 blocks), K-chunks of 384 ======================
__global__ __launch_bounds__(256) void gemm_h_kernel(
    const float* __restrict__ feat5, const float* __restrict__ feat8,
    const float* __restrict__ featcat,
    const float* __restrict__ W0, const float* __restrict__ W1,
    const float* __restrict__ W2, float* __restrict__ P)
{
  __shared__ __align__(16) float At[32][68];
  __shared__ __align__(16) float Bt[32][36];
  const int bid = blockIdx.x, tid = threadIdx.x;
  const float* X; const float* W; int Dm, split, jt, slice;
  if (bid < 32)      { X=feat5;   W=W0; Dm=D0; int l=bid;    split=l&1; jt=(l>>1)*32; slice=split; }
  else if (bid < 64) { X=feat8;   W=W1; Dm=D0; int l=bid-32; split=l&1; jt=(l>>1)*32; slice=SPA+split; }
  else               { X=featcat; W=W2; Dm=D2; int l=bid-64; split=l%6; jt=(l/6)*32;  slice=SPA+SPB+split; }
  float* Pb = P + (size_t)slice*BBHH;
  int k0 = split*384;
  int ti = tid >> 4, tj = tid & 15;
  float acc[4][2] = {};
  for (int ks = 0; ks < 384; ks += 32) {
    #pragma unroll
    for (int it = 0; it < 2; ++it) {
      int q = tid + it*256;
      int b = q & 63, kq = q >> 6;
      float4 v = *(const float4*)(X + (size_t)b*Dm + k0 + ks + kq*4);
      At[kq*4+0][b]=v.x; At[kq*4+1][b]=v.y; At[kq*4+2][b]=v.z; At[kq*4+3][b]=v.w;
    }
    {
      int j4 = tid & 7, kk = tid >> 3;
      float4 v = *(const float4*)(W + (size_t)(k0+ks+kk)*HH + jt + j4*4);
      *(float4*)&Bt[kk][j4*4] = v;
    }
    __syncthreads();
    #pragma unroll
    for (int k = 0; k < 32; ++k) {
      float4 a = *(const float4*)&At[k][ti*4];
      float2 b = *(const float2*)&Bt[k][tj*2];
      float av[4] = {a.x,a.y,a.z,a.w};
      float bv[2] = {b.x,b.y};
      #pragma unroll
      for (int r=0;r<4;++r)
        #pragma unroll
        for (int c=0;c<2;++c) acc[r][c] += av[r]*bv[c];
    }
    __syncthreads();
  }
  #pragma unroll
  for (int r=0;r<4;++r)
    #pragma unroll
    for (int c=0;c<2;++c)
      Pb[(size_t)(ti*4+r)*HH + jt + tj*2 + c] = acc[r][c];
}

// ===== K2: level0, 512 blocks (2/CU), XCD-localized E0 tiles ================
// xcd = bid&7 (round-robin assumption), slot = bid>>3.
// gt = xcd*16 + (slot>>2), btile = slot&3 -> all 4 row-slabs of one g-tile
// land on ONE XCD; E0 slice/XCD = 2.1 MB, fits 4 MB L2.
__global__ __launch_bounds__(256,2) void level0_kernel(
    const float* __restrict__ P, const float* __restrict__ b0v,
    const float* __restrict__ E0, float* __restrict__ p0out)
{
  __shared__ __align__(16) float At[32][20];   // [k][row16]
  __shared__ __align__(16) float Bt[32][68];   // [k][g64]
  const int bid = blockIdx.x, tid = threadIdx.x;
  const int slot = bid >> 3;
  const int gt = (bid & 7) * 16 + (slot >> 2);  // 0..127
  const int btile = slot & 3;                   // 16-row slab
  const int ti = tid >> 4, tj = tid & 15;
  float acc[4] = {};
  for (int ks = 0; ks < HH; ks += 32) {
    {
      int bb = tid & 15, kq = tid >> 4;
      float2 a = make_float2(0.f, 0.f);
      #pragma unroll
      for (int s=0;s<SPA;++s){
        float2 p = *(const float2*)(P + (size_t)s*BBHH
                        + (size_t)(btile*16+bb)*HH + ks + kq*2);
        a.x += p.x; a.y += p.y;
      }
      float2 bv = *(const float2*)(b0v + ks + kq*2);
      At[kq*2+0][bb] = geluf_(a.x + bv.x);
      At[kq*2+1][bb] = geluf_(a.y + bv.y);
    }
    #pragma unroll
    for (int it=0; it<2; ++it) {
      int q = tid + it*256; int g = q & 63, kq = q >> 6;
      float4 v = *(const float4*)(E0 + (size_t)(gt*64+g)*HH + ks + kq*4);
      Bt[kq*4+0][g]=v.x; Bt[kq*4+1][g]=v.y; Bt[kq*4+2][g]=v.z; Bt[kq*4+3][g]=v.w;
    }
    __syncthreads();
    #pragma unroll
    for (int k=0;k<32;++k) {
      float a = At[k][ti];
      float4 b = *(const float4*)&Bt[k][tj*4];
      acc[0] += a*b.x; acc[1] += a*b.y; acc[2] += a*b.z; acc[3] += a*b.w;
    }
    __syncthreads();
  }
  #pragma unroll
  for (int c=0;c<4;++c)
    p0out[(size_t)(btile*16 + ti)*NG0 + gt*64 + tj*4 + c] = sigmoidf_(acc[c]);
}

// ===== K3: redundant topk1 (x4) + h1-in-LDS + pipelined level1 gather =======
__global__ __launch_bounds__(256) void topk1_level1_kernel(
    const float* __restrict__ p0, const int* __restrict__ g0,
    const float* __restrict__ P, const float* __restrict__ b1v,
    const float* __restrict__ E1,
    int* __restrict__ cands1_i, float* __restrict__ o_c1,
    float* __restrict__ o_p1, float* __restrict__ o_w1)
{
  const int bid = blockIdx.x, tid = threadIdx.x;
  const int b = bid & 63, q = bid >> 6;
  const int lane = tid & 63, wid = tid >> 6;
  __shared__ float h1row[HH];
  __shared__ unsigned long long sbuf[256];
  __shared__ unsigned long long slist[256];
  __shared__ float s_sc[TK1];
  __shared__ int   s_idx[TK1];
  __shared__ int   scnt;
  {
    int j = tid*2;
    float ax=0.f, ay=0.f;
    #pragma unroll
    for (int s=0;s<SPB;++s){
      float2 v = *(const float2*)(P + (size_t)(SPA+s)*BBHH + (size_t)b*HH + j);
      ax += v.x; ay += v.y;
    }
    float2 bv = *(const float2*)(b1v + j);
    h1row[j]   = geluf_(ax + bv.x);
    h1row[j+1] = geluf_(ay + bv.y);
  }
  if (tid==0) scnt = 0;
  const float* row = p0 + (size_t)b*NG0;
  const float4* rp = (const float4*)(row + tid*32);
  unsigned long long m = 0ull;
  #pragma unroll
  for (int t=0;t<8;++t){
    float4 v = rp[t];
    unsigned i0 = (unsigned)(tid*32 + t*4);
    m = maxu64_(m, ((unsigned long long)__float_as_uint(v.x)<<32) | (unsigned long long)(0xFFFFFFFFu-(i0+0)));
    m = maxu64_(m, ((unsigned long long)__float_as_uint(v.y)<<32) | (unsigned long long)(0xFFFFFFFFu-(i0+1)));
    m = maxu64_(m, ((unsigned long long)__float_as_uint(v.z)<<32) | (unsigned long long)(0xFFFFFFFFu-(i0+2)));
    m = maxu64_(m, ((unsigned long long)__float_as_uint(v.w)<<32) | (unsigned long long)(0xFFFFFFFFu-(i0+3)));
  }
  __syncthreads();
  unsigned long long sk = bitonic256_desc(m, tid, sbuf);
  __syncthreads();
  sbuf[tid] = sk;
  __syncthreads();
  unsigned long long t32 = sbuf[31];
  __syncthreads();
  #pragma unroll
  for (int t=0;t<8;++t){
    float4 v = rp[t];
    unsigned i0 = (unsigned)(tid*32 + t*4);
    unsigned long long k0 = ((unsigned long long)__float_as_uint(v.x)<<32) | (unsigned long long)(0xFFFFFFFFu-(i0+0));
    unsigned long long k1 = ((unsigned long long)__float_as_uint(v.y)<<32) | (unsigned long long)(0xFFFFFFFFu-(i0+1));
    unsigned long long k2 = ((unsigned long long)__float_as_uint(v.z)<<32) | (unsigned long long)(0xFFFFFFFFu-(i0+2));
    unsigned long long k3 = ((unsigned long long)__float_as_uint(v.w)<<32) | (unsigned long long)(0xFFFFFFFFu-(i0+3));
    if (k0 >= t32) { int p = atomicAdd(&scnt,1); if (p<256) slist[p]=k0; }
    if (k1 >= t32) { int p = atomicAdd(&scnt,1); if (p<256) slist[p]=k1; }
    if (k2 >= t32) { int p = atomicAdd(&scnt,1); if (p<256) slist[p]=k2; }
    if (k3 >= t32) { int p = atomicAdd(&scnt,1); if (p<256) slist[p]=k3; }
  }
  __syncthreads();
  int cnt = scnt;
  unsigned long long key2 = (tid < cnt) ? slist[tid] : 0ull;
  key2 = bitonic256_desc(key2, tid, sbuf);
  __syncthreads();
  sbuf[tid] = key2;
  __syncthreads();
  if (tid < TK1) {
    unsigned long long w = sbuf[tid];
    s_idx[tid] = (int)(0xFFFFFFFFu - (unsigned)(w & 0xFFFFFFFFull));
    s_sc[tid]  = __uint_as_float((unsigned)(w>>32));
  }
  __syncthreads();
  if (q==0 && tid < NC1) {
    int k = tid >> 3, c = tid & 7;
    int cand = g0[(size_t)s_idx[k]*NC0 + c];
    cands1_i[(size_t)b*NC1+tid] = cand;
    o_c1[(size_t)b*NC1+tid] = (float)cand;
  }
  float4 ha = *(const float4*)&h1row[lane*8];
  float4 hb = *(const float4*)&h1row[lane*8+4];
  // hoist all 16 candidate ids (wave-uniform loads, issued in parallel)
  int cid[4][4];
  #pragma unroll
  for (int j=0;j<4;++j){
    int cbase = (q + 4*j)*16 + wid*4;
    #pragma unroll
    for (int u=0;u<4;++u)
      cid[j][u] = g0[(size_t)s_idx[(cbase+u)>>3]*NC0 + ((cbase+u)&7)];
  }
  // depth-2 pipelined gather
  float4 a0,c0,a1,c1,a2,c2,a3,c3;
  {
    const float4* p0e=(const float4*)(E1+(size_t)cid[0][0]*HH);
    const float4* p1e=(const float4*)(E1+(size_t)cid[0][1]*HH);
    const float4* p2e=(const float4*)(E1+(size_t)cid[0][2]*HH);
    const float4* p3e=(const float4*)(E1+(size_t)cid[0][3]*HH);
    a0=p0e[lane*2]; c0=p0e[lane*2+1]; a1=p1e[lane*2]; c1=p1e[lane*2+1];
    a2=p2e[lane*2]; c2=p2e[lane*2+1]; a3=p3e[lane*2]; c3=p3e[lane*2+1];
  }
  #pragma unroll
  for (int j=0;j<4;++j){
    float4 na0,nc0,na1,nc1,na2,nc2,na3,nc3;
    if (j<3){
      const float4* p0e=(const float4*)(E1+(size_t)cid[j+1][0]*HH);
      const float4* p1e=(const float4*)(E1+(size_t)cid[j+1][1]*HH);
      const float4* p2e=(const float4*)(E1+(size_t)cid[j+1][2]*HH);
      const float4* p3e=(const float4*)(E1+(size_t)cid[j+1][3]*HH);
      na0=p0e[lane*2]; nc0=p0e[lane*2+1]; na1=p1e[lane*2]; nc1=p1e[lane*2+1];
      na2=p2e[lane*2]; nc2=p2e[lane*2+1]; na3=p3e[lane*2]; nc3=p3e[lane*2+1];
    }
    int cbase = (q + 4*j)*16 + wid*4;
    float s0=dot8_(ha,hb,a0,c0), s1=dot8_(ha,hb,a1,c1);
    float s2=dot8_(ha,hb,a2,c2), s3=dot8_(ha,hb,a3,c3);
    #pragma unroll
    for (int off=1; off<64; off<<=1) {
      s0 += __shfl_xor(s0, off);
      s1 += __shfl_xor(s1, off);
      s2 += __shfl_xor(s2, off);
      s3 += __shfl_xor(s3, off);
    }
    if (lane==0) {
      float p;
      p = sigmoidf_(s0); o_p1[(size_t)b*NC1+cbase+0]=p; o_w1[(size_t)b*NC1+cbase+0]=p*s_sc[(cbase+0)>>3];
      p = sigmoidf_(s1); o_p1[(size_t)b*NC1+cbase+1]=p; o_w1[(size_t)b*NC1+cbase+1]=p*s_sc[(cbase+1)>>3];
      p = sigmoidf_(s2); o_p1[(size_t)b*NC1+cbase+2]=p; o_w1[(size_t)b*NC1+cbase+2]=p*s_sc[(cbase+2)>>3];
      p = sigmoidf_(s3); o_p1[(size_t)b*NC1+cbase+3]=p; o_w1[(size_t)b*NC1+cbase+3]=p*s_sc[(cbase+3)>>3];
    }
    if (j<3){ a0=na0;c0=nc0;a1=na1;c1=nc1;a2=na2;c2=nc2;a3=na3;c3=nc3; }
  }
}

// ===== K4: redundant topk2 (x8) + h2-in-LDS + pipelined level2 gather =======
// 512 blocks (2/CU): b = bid&63 (row), q = bid>>6 (eighth of the 704 cands)
__global__ __launch_bounds__(256,2) void topk2_level2_kernel(
    const float* __restrict__ p1, const int* __restrict__ cands1_i,
    const int* __restrict__ g1,
    const float* __restrict__ P, const float* __restrict__ b2v,
    const float* __restrict__ E2,
    float* __restrict__ o_c2, float* __restrict__ o_p2, float* __restrict__ o_w2)
{
  const int bid = blockIdx.x, tid = threadIdx.x;
  const int b = bid & 63, q = bid >> 6;     // q 0..7
  const int lane = tid & 63, wid = tid >> 6;
  __shared__ float h2row[HH];
  __shared__ unsigned long long sbuf[256];
  __shared__ float s_sc[TK2];
  __shared__ int   s_idx[TK2];
  __shared__ int   c1row[NC1];
  {
    int j = tid*2;
    float ax=0.f, ay=0.f;
    #pragma unroll
    for (int s=0;s<SPC;++s){
      float2 v = *(const float2*)(P + (size_t)(SPA+SPB+s)*BBHH + (size_t)b*HH + j);
      ax += v.x; ay += v.y;
    }
    float2 bv = *(const float2*)(b2v + j);
    h2row[j]   = geluf_(ax + bv.x);
    h2row[j+1] = geluf_(ay + bv.y);
  }
  c1row[tid] = cands1_i[(size_t)b*NC1 + tid];
  float v = p1[(size_t)b*NC1 + tid];
  unsigned long long key = ((unsigned long long)__float_as_uint(v)<<32) |
                           (unsigned long long)(0xFFFFFFFFu - (unsigned)tid);
  __syncthreads();
  key = bitonic256_desc(key, tid, sbuf);
  __syncthreads();
  sbuf[tid] = key;
  __syncthreads();
  if (tid < TK2) {
    unsigned long long w = sbuf[tid];
    s_idx[tid] = (int)(0xFFFFFFFFu - (unsigned)(w & 0xFFFFFFFFull));
    s_sc[tid]  = __uint_as_float((unsigned)(w>>32));
  }
  __syncthreads();
  if (q==0) {
    for (int e=tid; e<NC2; e+=256) {
      int k = e/NCH1, c = e - k*NCH1;
      int meta = c1row[s_idx[k]];
      int cand = g1[(size_t)meta*NCH1 + c];
      o_c2[(size_t)b*NC2+e] = (float)cand;
    }
  }
  // gather: 88 cands per block = 11 iters x 4 waves x 2 cands, pipelined
  float4 ha = *(const float4*)&h2row[lane*8];
  float4 hb = *(const float4*)&h2row[lane*8+4];
  int cid0[11], cid1[11];
  #pragma unroll
  for (int j=0;j<11;++j){
    int cb = q*88 + j*8 + wid*2;
    int k0i = (cb+0)/NCH1, c0i = (cb+0) - k0i*NCH1;
    int k1i = (cb+1)/NCH1, c1i = (cb+1) - k1i*NCH1;
    cid0[j] = g1[(size_t)c1row[s_idx[k0i]]*NCH1 + c0i];
    cid1[j] = g1[(size_t)c1row[s_idx[k1i]]*NCH1 + c1i];
  }
  float4 a0,c0,a1,c1;
  {
    const float4* p0e=(const float4*)(E2+(size_t)cid0[0]*HH);
    const float4* p1e=(const float4*)(E2+(size_t)cid1[0]*HH);
    a0=p0e[lane*2]; c0=p0e[lane*2+1]; a1=p1e[lane*2]; c1=p1e[lane*2+1];
  }
  #pragma unroll
  for (int j=0;j<11;++j){
    float4 na0,nc0,na1,nc1;
    if (j<10){
      const float4* p0e=(const float4*)(E2+(size_t)cid0[j+1]*HH);
      const float4* p1e=(const float4*)(E2+(size_t)cid1[j+1]*HH);
      na0=p0e[lane*2]; nc0=p0e[lane*2+1]; na1=p1e[lane*2]; nc1=p1e[lane*2+1];
    }
    int cbase = q*88 + j*8 + wid*2;
    int k0i = (cbase+0)/NCH1;
    int k1i = (cbase+1)/NCH1;
    float s0 = dot8_(ha,hb,a0,c0);
    float s1 = dot8_(ha,hb,a1,c1);
    #pragma unroll
    for (int off=1; off<64; off<<=1) {
      s0 += __shfl_xor(s0, off);
      s1 += __shfl_xor(s1, off);
    }
    if (lane==0) {
      float p;
      p = (s0==0.0f)?0.0f:sigmoidf_(s0); o_p2[(size_t)b*NC2+cbase+0]=p; o_w2[(size_t)b*NC2+cbase+0]=p*s_sc[k0i];
      p = (s1==0.0f)?0.0f:sigmoidf_(s1); o_p2[(size_t)b*NC2+cbase+1]=p; o_w2[(size_t)b*NC2+cbase+1]=p*s_sc[k1i];
    }
    if (j<10){ a0=na0;c0=nc0;a1=na1;c1=nc1; }
  }
}

extern "C" void kernel_launch(void* const* d_in, const int* in_sizes, int n_in,
                              void* d_out, int out_size, void* d_ws, size_t ws_size,
                              hipStream_t stream) {
  const float* feat5   = (const float*)d_in[0];
  const float* feat8   = (const float*)d_in[1];
  const float* featcat = (const float*)d_in[2];
  const float* W0 = (const float*)d_in[3];
  const float* b0 = (const float*)d_in[4];
  const float* W1 = (const float*)d_in[5];
  const float* b1 = (const float*)d_in[6];
  const float* W2 = (const float*)d_in[7];
  const float* b2 = (const float*)d_in[8];
  const float* E0 = (const float*)d_in[9];
  const float* E1 = (const float*)d_in[10];
  const float* E2 = (const float*)d_in[11];
  const int*   g0 = (const int*)d_in[12];
  const int*   g1 = (const int*)d_in[13];

  float* out = (float*)d_out;
  float* ws  = (float*)d_ws;

  size_t off = 0;
  float* P = ws + off; off += (size_t)NSL*BBHH;
  int*   cands1_i = (int*)(ws + off); off += (size_t)BB*NC1;

  float* o_p0 = out;
  float* o_p1 = o_p0 + (size_t)BB*NG0;
  float* o_p2 = o_p1 + (size_t)BB*NC1;
  float* o_w1 = o_p2 + (size_t)BB*NC2;
  float* o_w2 = o_w1 + (size_t)BB*NC1;
  float* o_c1 = o_w2 + (size_t)BB*NC2;
  float* o_c2 = o_c1 + (size_t)BB*NC1;

  gemm_h_kernel<<<dim3(160), dim3(256), 0, stream>>>(feat5, feat8, featcat, W0, W1, W2, P);
  level0_kernel<<<dim3(512), dim3(256), 0, stream>>>(P, b0, E0, o_p0);
  topk1_level1_kernel<<<dim3(256), dim3(256), 0, stream>>>(o_p0, g0, P, b1, E1,
      cands1_i, o_c1, o_p1, o_w1);
  topk2_level2_kernel<<<dim3(512), dim3(256), 0, stream>>>(o_p1, cands1_i, g1, P, b2, E2,
      o_c2, o_p2, o_w2);
}